// Round 7
// baseline (1873.653 us; speedup 1.0000x reference)
//
#include <hip/hip_runtime.h>
#include <stdint.h>

// ---------------------------------------------------------------------------
// DGCNN forward on MI355X. All fp32. B=8 graphs x N=2048 nodes, D0=6, K=10.
// BN folded into following layer weights; max-pools done on raw activations
// via monotone-affine trick; x5 branch of m0 reduced to [8,1024]@[1024,256].
// R6: kNN occupancy fix — j-range split in half per block (1024 blocks =
// 4 blocks/CU), BK=8 + two-phase 16-row merge cut LDS 47.6->28.9 KB, reg
// prefetch dropped (R5 evidence: ~no gain; costs VGPR). Partial top-10s to
// part[T][2][10], exact 20-entry final merge kernel.
// ---------------------------------------------------------------------------

constexpr int T  = 16384;   // total nodes
constexpr int NBG = 8;      // graphs
constexpr int NN = 2048;    // nodes per graph
constexpr int KK = 10;      // kNN
constexpr float BN_EPS = 1e-5f;

__device__ __forceinline__ unsigned fkey(float f) {
  unsigned u = __float_as_uint(f);
  return (u & 0x80000000u) ? ~u : (u | 0x80000000u);
}
__device__ __forceinline__ float funkey(unsigned k) {
  unsigned u = (k & 0x80000000u) ? (k ^ 0x80000000u) : ~k;
  return __uint_as_float(u);
}

__device__ __forceinline__ void ins10(unsigned long long (&b)[KK],
                                      unsigned long long v) {
  b[KK - 1] = v;
#pragma unroll
  for (int s = KK - 1; s > 0; --s)
    if (b[s] < b[s - 1]) {
      unsigned long long t2 = b[s]; b[s] = b[s - 1]; b[s - 1] = t2;
    }
}

// ---------------------------------------------------------------- zero init
__global__ void zero_kernel(float* __restrict__ stats,
                            unsigned* __restrict__ cmax, unsigned* __restrict__ cmin) {
  const int gid = blockIdx.x * blockDim.x + threadIdx.x;
  if (gid < 9 * 2048) stats[gid] = 0.f;
  if (gid < NBG * 1024) { cmax[gid] = 0u; cmin[gid] = 0xFFFFFFFFu; }
}

// ---------------------------------------------------------------- row norms
__global__ void row_sq_kernel(const float* __restrict__ X, int ldx, int D,
                              float* __restrict__ sq) {
  const int t = blockIdx.x * blockDim.x + threadIdx.x;
  if (t >= T) return;
  const float* xr = X + (size_t)t * ldx;
  float s = 0.f;
  for (int d = 0; d < D; ++d) s = fmaf(xr[d], xr[d], s);
  sq[t] = s;
}

// ---------------------------------------------------------------- kNN (j-split)
// Block: 32 rows x 1024 j (half the graph; jh=blk&1 picks which half).
// 256 threads: tg=tid>>4 owns rows {2tg,2tg+1}, tc=tid&15 owns cols
// [tc*32,+32) of each 512-col j-tile (2 tiles). Metric m = sq[j]-2*dot
// (row-constant sq[i] dropped; same order). Per-thread running top-10 with
// exact row-global reject threshold (min over the 16 tc lanes' 10th-best).
// In-block merge in two 16-row phases -> part[T][2][10].
template<int D>
__global__ __launch_bounds__(256) void knn_split_kernel(
    const float* __restrict__ X, int ldx,
    const float* __restrict__ sq,
    unsigned long long* __restrict__ part /* [T][2][10] */) {
  constexpr int BK = (D == 64) ? 8 : 6;
  constexpr int AF = D * 32;          // As floats [k][row]
  constexpr int BF = BK * 576;        // Bs floats [k][g][36] (16 groups 32+4 pad)
  constexpr int TOTF = AF + BF + 576; // + sqs [g][36]
  constexpr int MRGF = 16 * 161 * 2;  // merge: 16 rows x 161 u64, two phases
  constexpr int SMEMF = (TOTF > MRGF) ? TOTF : MRGF;
  __shared__ __align__(16) float smem[SMEMF];
  float* As = smem;
  float* Bs = smem + AF;
  float* sqs = smem + AF + BF;

  const int tid = threadIdx.x;
  const int blk = blockIdx.x;
  const int b = blk >> 7;             // graph
  const int ib = (blk >> 1) & 63;     // 32-row group
  const int jh = blk & 1;             // j half
  const int i0 = b * NN + ib * 32;
  const int jg0 = b * NN + jh * 1024;
  const int tg = tid >> 4, tc = tid & 15;

  // ---- stage A once: [k][row]
  if constexpr (D == 64) {
    const int r = tid & 31, ks = (tid >> 5) * 8;
    const float* rp = &X[(size_t)(i0 + r) * ldx + ks];
    const float4 v0 = *(const float4*)rp;
    const float4 v1 = *(const float4*)(rp + 4);
    As[(ks + 0) * 32 + r] = v0.x; As[(ks + 1) * 32 + r] = v0.y;
    As[(ks + 2) * 32 + r] = v0.z; As[(ks + 3) * 32 + r] = v0.w;
    As[(ks + 4) * 32 + r] = v1.x; As[(ks + 5) * 32 + r] = v1.y;
    As[(ks + 6) * 32 + r] = v1.z; As[(ks + 7) * 32 + r] = v1.w;
  } else {
    const int r = tid >> 3, k = tid & 7;
    if (k < D) As[k * 32 + r] = X[(size_t)(i0 + r) * ldx + k];
  }

  const unsigned long long initk = 0xFF800000FFFFFFFFULL;  // key(+inf)
  unsigned long long bst0[KK], bst1[KK];
#pragma unroll
  for (int s = 0; s < KK; ++s) { bst0[s] = initk; bst1[s] = initk; }
  const float FINF = __int_as_float(0x7F800000);
  float thr0 = FINF, thr1 = FINF;
  float rowThr0 = FINF, rowThr1 = FINF;

  for (int jt = 0; jt < 2; ++jt) {
    const int jtbase = jg0 + jt * 512;
    float acc0[32] = {}, acc1[32] = {};

    if constexpr (D == 64) {
      for (int kb = 0; kb < 64; kb += 8) {
        __syncthreads();  // prior consumers of Bs/sqs done
#pragma unroll
        for (int h = 0; h < 2; ++h) {
          const int c = tid + h * 256;
          const float* rp = &X[(size_t)(jtbase + c) * ldx + kb];
          const float4 v0 = *(const float4*)rp;
          const float4 v1 = *(const float4*)(rp + 4);
          const int co = (c >> 5) * 36 + (c & 31);
          Bs[0 * 576 + co] = v0.x; Bs[1 * 576 + co] = v0.y;
          Bs[2 * 576 + co] = v0.z; Bs[3 * 576 + co] = v0.w;
          Bs[4 * 576 + co] = v1.x; Bs[5 * 576 + co] = v1.y;
          Bs[6 * 576 + co] = v1.z; Bs[7 * 576 + co] = v1.w;
          if (kb == 0) sqs[co] = sq[jtbase + c];
        }
        __syncthreads();
#pragma unroll
        for (int kk = 0; kk < 8; ++kk) {
          const float2 av = *(const float2*)&As[(kb + kk) * 32 + 2 * tg];
          const float a0 = av.x, a1 = av.y;
          const float* bp = &Bs[kk * 576 + tc * 36];
#pragma unroll
          for (int c4 = 0; c4 < 8; ++c4) {
            const float4 bv = *(const float4*)(bp + c4 * 4);
            acc0[c4 * 4 + 0] = fmaf(a0, bv.x, acc0[c4 * 4 + 0]);
            acc0[c4 * 4 + 1] = fmaf(a0, bv.y, acc0[c4 * 4 + 1]);
            acc0[c4 * 4 + 2] = fmaf(a0, bv.z, acc0[c4 * 4 + 2]);
            acc0[c4 * 4 + 3] = fmaf(a0, bv.w, acc0[c4 * 4 + 3]);
            acc1[c4 * 4 + 0] = fmaf(a1, bv.x, acc1[c4 * 4 + 0]);
            acc1[c4 * 4 + 1] = fmaf(a1, bv.y, acc1[c4 * 4 + 1]);
            acc1[c4 * 4 + 2] = fmaf(a1, bv.z, acc1[c4 * 4 + 2]);
            acc1[c4 * 4 + 3] = fmaf(a1, bv.w, acc1[c4 * 4 + 3]);
          }
        }
      }
    } else {  // D == 6: one staging step per tile
      __syncthreads();
#pragma unroll
      for (int h = 0; h < 2; ++h) {
        const int c = tid + h * 256;
        const float* rp = &X[(size_t)(jtbase + c) * ldx];
        const int co = (c >> 5) * 36 + (c & 31);
#pragma unroll
        for (int k = 0; k < 6; ++k) Bs[k * 576 + co] = rp[k];
        sqs[co] = sq[jtbase + c];
      }
      __syncthreads();
#pragma unroll
      for (int kk = 0; kk < 6; ++kk) {
        const float2 av = *(const float2*)&As[kk * 32 + 2 * tg];
        const float a0 = av.x, a1 = av.y;
        const float* bp = &Bs[kk * 576 + tc * 36];
#pragma unroll
        for (int c4 = 0; c4 < 8; ++c4) {
          const float4 bv = *(const float4*)(bp + c4 * 4);
          acc0[c4 * 4 + 0] = fmaf(a0, bv.x, acc0[c4 * 4 + 0]);
          acc0[c4 * 4 + 1] = fmaf(a0, bv.y, acc0[c4 * 4 + 1]);
          acc0[c4 * 4 + 2] = fmaf(a0, bv.z, acc0[c4 * 4 + 2]);
          acc0[c4 * 4 + 3] = fmaf(a0, bv.w, acc0[c4 * 4 + 3]);
          acc1[c4 * 4 + 0] = fmaf(a1, bv.x, acc1[c4 * 4 + 0]);
          acc1[c4 * 4 + 1] = fmaf(a1, bv.y, acc1[c4 * 4 + 1]);
          acc1[c4 * 4 + 2] = fmaf(a1, bv.z, acc1[c4 * 4 + 2]);
          acc1[c4 * 4 + 3] = fmaf(a1, bv.w, acc1[c4 * 4 + 3]);
        }
      }
    }

    // ---- selection for tile jt: gate on row-global + local thresholds.
    // Exact: per-thread j strictly increases, so equal-m later-j is correctly
    // rejected by the strict < on the local threshold; rowThr is a proven
    // reject bound (some lane already holds 10 better).
#pragma unroll
    for (int c4 = 0; c4 < 8; ++c4) {
      const float4 sv = *(const float4*)&sqs[tc * 36 + c4 * 4];
      const float svv[4] = {sv.x, sv.y, sv.z, sv.w};
#pragma unroll
      for (int u = 0; u < 4; ++u) {
        const int c = c4 * 4 + u;
        const int j = jtbase + tc * 32 + c;
        const float m0 = fmaf(-2.f, acc0[c], svv[u]);
        if (m0 <= rowThr0 && m0 < thr0) {
          ins10(bst0, ((unsigned long long)fkey(m0) << 32) | (unsigned)j);
          thr0 = funkey((unsigned)(bst0[KK - 1] >> 32));
        }
        const float m1 = fmaf(-2.f, acc1[c], svv[u]);
        if (m1 <= rowThr1 && m1 < thr1) {
          ins10(bst1, ((unsigned long long)fkey(m1) << 32) | (unsigned)j);
          thr1 = funkey((unsigned)(bst1[KK - 1] >> 32));
        }
      }
    }
    float r0 = thr0, r1 = thr1;
#pragma unroll
    for (int d = 1; d < 16; d <<= 1) {
      r0 = fminf(r0, __shfl_xor(r0, d, 64));
      r1 = fminf(r1, __shfl_xor(r1, d, 64));
    }
    rowThr0 = r0; rowThr1 = r1;
  }

  // ---- merge: 16 lists per row, two 16-row phases (LDS stays 20.6 KB).
  unsigned long long* msc = (unsigned long long*)smem;  // [16 rows][161]
  for (int half = 0; half < 2; ++half) {
    __syncthreads();
    if ((tg >> 3) == half) {
      const int r0l = 2 * tg - 16 * half;
#pragma unroll
      for (int s = 0; s < KK; ++s) {
        msc[(size_t)r0l * 161 + tc * 10 + s] = bst0[s];
        msc[(size_t)(r0l + 1) * 161 + tc * 10 + s] = bst1[s];
      }
    }
    __syncthreads();
    if (tid < 16) {
      const unsigned long long* p = &msc[(size_t)tid * 161];
      unsigned long long best[KK];
#pragma unroll
      for (int s = 0; s < KK; ++s) best[s] = ~0ULL;
      for (int q = 0; q < 160; ++q) {
        const unsigned long long v = p[q];
        if (v < best[KK - 1]) ins10(best, v);
      }
      unsigned long long* o =
          part + ((size_t)(i0 + half * 16 + tid) * 2 + jh) * KK;
#pragma unroll
      for (int s = 0; s < KK; ++s) o[s] = best[s];
    }
  }
}

// final merge of the two j-half partials (20 entries) -> idx
__global__ void knn_merge2_kernel(const unsigned long long* __restrict__ part,
                                  int* __restrict__ idx) {
  const int i = blockIdx.x * blockDim.x + threadIdx.x;
  if (i >= T) return;
  const unsigned long long* p = part + (size_t)i * 2 * KK;
  unsigned long long best[KK];
#pragma unroll
  for (int s = 0; s < KK; ++s) best[s] = ~0ULL;
  for (int q = 0; q < 2 * KK; ++q) {
    const unsigned long long v = p[q];
    if (v < best[KK - 1]) ins10(best, v);
  }
#pragma unroll
  for (int s = 0; s < KK; ++s) idx[i * KK + s] = (int)(best[s] & 0xffffffffu);
}

// ---------------------------------------------------------------- edge MLP0
// h = relu(b0 + xi@(W_A - W_B) + xj@W_B). Wave per 8 nodes, lane = out chan.
template<int D>
__global__ __launch_bounds__(256) void mlp0_kernel(
    const float* __restrict__ X, int ldx,
    const int* __restrict__ idx,
    const float* __restrict__ w0, const float* __restrict__ b0,
    float* __restrict__ eh0, float* __restrict__ stat) {
  const int wv = threadIdx.x >> 6, lane = threadIdx.x & 63;
  const int t0 = (blockIdx.x * 4 + wv) * 8;
  float wB[D], wd[D];
#pragma unroll
  for (int d = 0; d < D; ++d) {
    const float a = w0[d * 64 + lane];
    const float b = w0[(D + d) * 64 + lane];
    wB[d] = b; wd[d] = a - b;
  }
  const float bb = b0[lane];
  float s1 = 0.f, s2 = 0.f;
  for (int tt = 0; tt < 8; ++tt) {
    const int t = t0 + tt;
    const float* xr = X + (size_t)t * ldx;
    float hb = bb;
    if constexpr (D == 64) {
      float h0 = 0.f, h1 = 0.f;
#pragma unroll
      for (int q = 0; q < 16; ++q) {
        const float4 v = *(const float4*)(xr + q * 4);
        h0 = fmaf(v.x, wd[4 * q + 0], h0);
        h1 = fmaf(v.y, wd[4 * q + 1], h1);
        h0 = fmaf(v.z, wd[4 * q + 2], h0);
        h1 = fmaf(v.w, wd[4 * q + 3], h1);
      }
      hb += h0 + h1;
    } else {
#pragma unroll
      for (int d = 0; d < D; ++d) hb = fmaf(xr[d], wd[d], hb);
    }
    for (int k = 0; k < KK; ++k) {
      const int jg = idx[t * KK + k];
      const float* yr = X + (size_t)jg * ldx;
      float h = hb;
      if constexpr (D == 64) {
        float h0 = 0.f, h1 = 0.f;
#pragma unroll
        for (int q = 0; q < 16; ++q) {
          const float4 v = *(const float4*)(yr + q * 4);
          h0 = fmaf(v.x, wB[4 * q + 0], h0);
          h1 = fmaf(v.y, wB[4 * q + 1], h1);
          h0 = fmaf(v.z, wB[4 * q + 2], h0);
          h1 = fmaf(v.w, wB[4 * q + 3], h1);
        }
        h += h0 + h1;
      } else {
#pragma unroll
        for (int d = 0; d < D; ++d) h = fmaf(yr[d], wB[d], h);
      }
      h = fmaxf(h, 0.f);
      eh0[(size_t)(t * KK + k) * 64 + lane] = h;
      s1 += h;
      s2 = fmaf(h, h, s2);
    }
  }
  __shared__ float ls[4][64];
  ls[wv][lane] = s1;
  __syncthreads();
  if (wv == 0) atomicAdd(&stat[lane], ls[0][lane] + ls[1][lane] + ls[2][lane] + ls[3][lane]);
  __syncthreads();
  ls[wv][lane] = s2;
  __syncthreads();
  if (wv == 0) atomicAdd(&stat[1024 + lane], ls[0][lane] + ls[1][lane] + ls[2][lane] + ls[3][lane]);
}

// ---------------------------------------------------------------- BN fold
__global__ void fold_kernel(const float* __restrict__ stat, float cntInv,
                            const float* __restrict__ g, const float* __restrict__ be,
                            const float* __restrict__ W, const float* __restrict__ bias,
                            float* __restrict__ Wf, float* __restrict__ bf,
                            int Cin, int Cout) {
  const int gid = blockIdx.x * blockDim.x + threadIdx.x;
  const int nW = Cin * Cout;
  if (gid < nW) {
    const int d = gid / Cout;
    const float mean = stat[d] * cntInv;
    const float var = fmaf(-mean, mean, stat[1024 + d] * cntInv);
    const float a = g[d] * rsqrtf(var + BN_EPS);
    Wf[gid] = a * W[gid];
  } else if (gid < nW + Cout) {
    const int j = gid - nW;
    float acc = bias[j];
    for (int d = 0; d < Cin; ++d) {
      const float mean = stat[d] * cntInv;
      const float var = fmaf(-mean, mean, stat[1024 + d] * cntInv);
      const float a = g[d] * rsqrtf(var + BN_EPS);
      const float c = fmaf(-mean, a, be[d]);
      acc = fmaf(c, W[d * Cout + j], acc);
    }
    bf[j] = acc;
  }
}

// ---------------------------------------------------------------- edge MLP1
__global__ __launch_bounds__(256) void mlp1_kernel(
    const float* __restrict__ eh0,
    const float* __restrict__ w1f, const float* __restrict__ b1f,
    float* __restrict__ xmax, float* __restrict__ xmin,
    float* __restrict__ stat) {
  const int wv = threadIdx.x >> 6, lane = threadIdx.x & 63;
  const int t0 = (blockIdx.x * 4 + wv) * 8;
  float wc[64];
#pragma unroll
  for (int d = 0; d < 64; ++d) wc[d] = w1f[d * 64 + lane];
  const float bb = b1f[lane];
  float s1 = 0.f, s2 = 0.f;
  for (int tt = 0; tt < 8; ++tt) {
    const int t = t0 + tt;
    float mx = -3.4e38f, mn = 3.4e38f;
#pragma unroll 2
    for (int k = 0; k < KK; ++k) {
      const float* er = eh0 + (size_t)(t * KK + k) * 64;
      float h0 = bb, h1 = 0.f;
#pragma unroll
      for (int q = 0; q < 16; ++q) {
        const float4 v = *(const float4*)(er + q * 4);
        h0 = fmaf(v.x, wc[4 * q + 0], h0);
        h1 = fmaf(v.y, wc[4 * q + 1], h1);
        h0 = fmaf(v.z, wc[4 * q + 2], h0);
        h1 = fmaf(v.w, wc[4 * q + 3], h1);
      }
      const float h = fmaxf(h0 + h1, 0.f);
      mx = fmaxf(mx, h); mn = fminf(mn, h);
      s1 += h; s2 = fmaf(h, h, s2);
    }
    xmax[t * 64 + lane] = mx;
    xmin[t * 64 + lane] = mn;
  }
  __shared__ float ls[4][64];
  ls[wv][lane] = s1;
  __syncthreads();
  if (wv == 0) atomicAdd(&stat[lane], ls[0][lane] + ls[1][lane] + ls[2][lane] + ls[3][lane]);
  __syncthreads();
  ls[wv][lane] = s2;
  __syncthreads();
  if (wv == 0) atomicAdd(&stat[1024 + lane], ls[0][lane] + ls[1][lane] + ls[2][lane] + ls[3][lane]);
}

// ---------------------------------------------------------------- conv output
__global__ void conv_out_kernel(const float* __restrict__ xmax, const float* __restrict__ xmin,
                                const float* __restrict__ stat, float cntInv,
                                const float* __restrict__ g, const float* __restrict__ be,
                                float* __restrict__ cat, int coff) {
  const int gid = blockIdx.x * blockDim.x + threadIdx.x;
  const int c = gid & 63, t = gid >> 6;
  const float mean = stat[c] * cntInv;
  const float var = fmaf(-mean, mean, stat[1024 + c] * cntInv);
  const float a = g[c] * rsqrtf(var + BN_EPS);
  const float cc = fmaf(-mean, a, be[c]);
  const float v = (a >= 0.f) ? fmaf(a, xmax[gid], cc) : fmaf(a, xmin[gid], cc);
  cat[(size_t)t * 192 + coff + c] = v;
}

// ---------------------------------------------------------------- generic GEMM
__global__ __launch_bounds__(256) void gemm_kernel(
    const float* __restrict__ A, int lda,
    const float* __restrict__ Bw, int ldb,
    const float* __restrict__ bias, int biasPerGraph,
    float* __restrict__ C,
    float* __restrict__ stat,
    unsigned* __restrict__ cmax, unsigned* __restrict__ cmin,
    int Kdim, int Ncols) {
  __shared__ float As[32][68];   // transposed A tile [k][row], padded
  __shared__ float Bs[32][64];
  const int tid = threadIdx.x;
  const int nbx = Ncols >> 6;
  const int bx = blockIdx.x % nbx, by = blockIdx.x / nbx;
  const int row0 = by << 6, col0 = bx << 6;
  const int tx = tid & 15, ty = tid >> 4;
  float acc[4][4] = {};
  for (int kb = 0; kb < Kdim; kb += 32) {
    __syncthreads();
    {
      const int r = tid >> 3, fc = tid & 7;
#pragma unroll
      for (int h = 0; h < 2; ++h) {
        const int rr = r + h * 32;
        const float4 va = *(const float4*)&A[(size_t)(row0 + rr) * lda + kb + fc * 4];
        As[fc * 4 + 0][rr] = va.x; As[fc * 4 + 1][rr] = va.y;
        As[fc * 4 + 2][rr] = va.z; As[fc * 4 + 3][rr] = va.w;
      }
      const int kr = tid >> 4, c4 = tid & 15;
#pragma unroll
      for (int h = 0; h < 2; ++h) {
        const int k2 = kr + h * 16;
        *(float4*)&Bs[k2][c4 * 4] =
            *(const float4*)&Bw[(size_t)(kb + k2) * ldb + col0 + c4 * 4];
      }
    }
    __syncthreads();
#pragma unroll
    for (int k = 0; k < 32; ++k) {
      const float4 av = *(const float4*)&As[k][ty * 4];
      const float4 bv = *(const float4*)&Bs[k][tx * 4];
      const float a4[4] = {av.x, av.y, av.z, av.w};
      const float b4[4] = {bv.x, bv.y, bv.z, bv.w};
#pragma unroll
      for (int i = 0; i < 4; ++i)
#pragma unroll
        for (int j = 0; j < 4; ++j) acc[i][j] = fmaf(a4[i], b4[j], acc[i][j]);
    }
  }
  const int graph = row0 >> 11;
  const float* bp = bias + (biasPerGraph ? graph * Ncols : 0) + col0 + tx * 4;
  float v[4][4];
#pragma unroll
  for (int j = 0; j < 4; ++j) {
    const float bj = bp[j];
#pragma unroll
    for (int i = 0; i < 4; ++i) v[i][j] = fmaxf(acc[i][j] + bj, 0.f);
  }
  if (C) {
#pragma unroll
    for (int i = 0; i < 4; ++i) {
      const float4 st = make_float4(v[i][0], v[i][1], v[i][2], v[i][3]);
      *(float4*)&C[(size_t)(row0 + ty * 4 + i) * Ncols + col0 + tx * 4] = st;
    }
  }
  if (stat) {
    __syncthreads();
#pragma unroll
    for (int j = 0; j < 4; ++j)
      As[ty][tx * 4 + j] = v[0][j] + v[1][j] + v[2][j] + v[3][j];
    __syncthreads();
    if (tid < 64) {
      float s = 0.f;
#pragma unroll
      for (int q = 0; q < 16; ++q) s += As[q][tid];
      atomicAdd(&stat[col0 + tid], s);
    }
    __syncthreads();
#pragma unroll
    for (int j = 0; j < 4; ++j) {
      float s = 0.f;
#pragma unroll
      for (int i = 0; i < 4; ++i) s = fmaf(v[i][j], v[i][j], s);
      As[ty][tx * 4 + j] = s;
    }
    __syncthreads();
    if (tid < 64) {
      float s = 0.f;
#pragma unroll
      for (int q = 0; q < 16; ++q) s += As[q][tid];
      atomicAdd(&stat[1024 + col0 + tid], s);
    }
    if (cmax) {
      __syncthreads();
#pragma unroll
      for (int j = 0; j < 4; ++j)
        As[ty][tx * 4 + j] = fmaxf(fmaxf(v[0][j], v[1][j]), fmaxf(v[2][j], v[3][j]));
      __syncthreads();
      if (tid < 64) {
        float s = As[0][tid];
#pragma unroll
        for (int q = 1; q < 16; ++q) s = fmaxf(s, As[q][tid]);
        atomicMax(&cmax[graph * Ncols + col0 + tid], fkey(s));
      }
      __syncthreads();
#pragma unroll
      for (int j = 0; j < 4; ++j)
        As[ty][tx * 4 + j] = fminf(fminf(v[0][j], v[1][j]), fminf(v[2][j], v[3][j]));
      __syncthreads();
      if (tid < 64) {
        float s = As[0][tid];
#pragma unroll
        for (int q = 1; q < 16; ++q) s = fminf(s, As[q][tid]);
        atomicMin(&cmin[graph * Ncols + col0 + tid], fkey(s));
      }
    }
  }
}

// ---------------------------------------------------------------- pooled (normalized)
__global__ void pool_finalize_kernel(const unsigned* __restrict__ cmax,
                                     const unsigned* __restrict__ cmin,
                                     const float* __restrict__ stat, float cntInv,
                                     const float* __restrict__ g, const float* __restrict__ be,
                                     float* __restrict__ pooled) {
  const int gid = blockIdx.x * blockDim.x + threadIdx.x;
  if (gid >= NBG * 1024) return;
  const int col = gid & 1023;
  const float mean = stat[col] * cntInv;
  const float var = fmaf(-mean, mean, stat[1024 + col] * cntInv);
  const float a = g[col] * rsqrtf(var + BN_EPS);
  const float cc = fmaf(-mean, a, be[col]);
  const float fx = funkey(cmax[gid]), fn = funkey(cmin[gid]);
  pooled[gid] = (a >= 0.f) ? fmaf(a, fx, cc) : fmaf(a, fn, cc);
}

// po[b][j] = m0_b[j] + pooled[b] @ m0_w[192:1216]
__global__ void po_gemm_kernel(const float* __restrict__ pooled,
                               const float* __restrict__ w2,
                               const float* __restrict__ m0b,
                               float* __restrict__ po) {
  const int b = blockIdx.x, j = threadIdx.x;
  const float* pr = pooled + b * 1024;
  float a0 = m0b[j], a1 = 0.f, a2 = 0.f, a3 = 0.f;
  for (int d = 0; d < 1024; d += 4) {
    a0 = fmaf(pr[d + 0], w2[(size_t)(d + 0) * 256 + j], a0);
    a1 = fmaf(pr[d + 1], w2[(size_t)(d + 1) * 256 + j], a1);
    a2 = fmaf(pr[d + 2], w2[(size_t)(d + 2) * 256 + j], a2);
    a3 = fmaf(pr[d + 3], w2[(size_t)(d + 3) * 256 + j], a3);
  }
  po[b * 256 + j] = (a0 + a1) + (a2 + a3);
}

// out[t] = hm1[t] @ m2f + b2f   (wave per row, shuffle reduce)
__global__ __launch_bounds__(256) void m2_gemv_kernel(
    const float* __restrict__ hm1, const float* __restrict__ m2f,
    const float* __restrict__ m2fb, float* __restrict__ out) {
  const int wv = threadIdx.x >> 6, lane = threadIdx.x & 63;
  const int t = blockIdx.x * 4 + wv;
  const float* r = hm1 + (size_t)t * 128;
  float v = fmaf(r[lane], m2f[lane], r[64 + lane] * m2f[64 + lane]);
  for (int off = 32; off; off >>= 1) v += __shfl_down(v, off);
  if (lane == 0) out[t] = v + m2fb[0];
}

// ---------------------------------------------------------------------------
extern "C" void kernel_launch(void* const* d_in, const int* in_sizes, int n_in,
                              void* d_out, int out_size, void* d_ws, size_t ws_size,
                              hipStream_t stream) {
  const float* x = (const float*)d_in[0];
  const float* c_w0[3] = {(const float*)d_in[1], (const float*)d_in[9],  (const float*)d_in[17]};
  const float* c_b0[3] = {(const float*)d_in[2], (const float*)d_in[10], (const float*)d_in[18]};
  const float* c_g0[3] = {(const float*)d_in[3], (const float*)d_in[11], (const float*)d_in[19]};
  const float* c_be0[3]= {(const float*)d_in[4], (const float*)d_in[12], (const float*)d_in[20]};
  const float* c_w1[3] = {(const float*)d_in[5], (const float*)d_in[13], (const float*)d_in[21]};
  const float* c_b1[3] = {(const float*)d_in[6], (const float*)d_in[14], (const float*)d_in[22]};
  const float* c_g1[3] = {(const float*)d_in[7], (const float*)d_in[15], (const float*)d_in[23]};
  const float* c_be1[3]= {(const float*)d_in[8], (const float*)d_in[16], (const float*)d_in[24]};
  const float* l1_w = (const float*)d_in[25];
  const float* l1_b = (const float*)d_in[26];
  const float* l1_g = (const float*)d_in[27];
  const float* l1_be= (const float*)d_in[28];
  const float* m0_w = (const float*)d_in[29];
  const float* m0_b = (const float*)d_in[30];
  const float* m0_g = (const float*)d_in[31];
  const float* m0_be= (const float*)d_in[32];
  const float* m1_w = (const float*)d_in[33];
  const float* m1_b = (const float*)d_in[34];
  const float* m1_g = (const float*)d_in[35];
  const float* m1_be= (const float*)d_in[36];
  const float* m2_w = (const float*)d_in[37];
  const float* m2_b = (const float*)d_in[38];
  float* out = (float*)d_out;

  char* ws = (char*)d_ws;
  float*    stats  = (float*)(ws + 0);          // 9 stages x 2048 floats
  unsigned* cmax   = (unsigned*)(ws + 73728);   // [8][1024]
  unsigned* cmin   = (unsigned*)(ws + 106496);
  float*    pooled = (float*)(ws + 139264);     // [8][1024]
  float*    po     = (float*)(ws + 172032);     // [8][256]
  float*    w1f    = (float*)(ws + 180224);     // 64x64
  float*    b1f    = (float*)(ws + 196608);     // 64
  float*    m1f    = (float*)(ws + 196864);     // 256x128
  float*    m1fb   = (float*)(ws + 327936);     // 128
  float*    m2f    = (float*)(ws + 328448);     // 128
  float*    m2fb   = (float*)(ws + 328960);     // 1
  float*    sq     = (float*)(ws + 329216);     // [T]
  int*      idx    = (int*)  (ws + 394752);     // [T][10]
  float*    xmax   = (float*)(ws + 1050112);    // [T][64]
  float*    xmin   = (float*)(ws + 5244416);    // [T][64]
  float*    cat    = (float*)(ws + 9438720);    // [T][192]
  char*     regA   = ws + 22021632;             // 42 MB scratch, time-shared
  unsigned long long* part = (unsigned long long*)regA;  // [T][2][10] u64
  float*    eh0    = (float*)regA;              // [T*10][64] (after knn done)
  float*    hm0    = (float*)regA;              // [T][256]  (after convs)
  float*    hm1    = (float*)(regA + 16777216); // [T][128]

  const float cInvE = 1.f / (float)(T * KK);
  const float cInvT = 1.f / (float)T;

  zero_kernel<<<72, 256, 0, stream>>>(stats, cmax, cmin);

  for (int cidx = 0; cidx < 3; ++cidx) {
    const float* Xin; int ldx, Din;
    const int coff = cidx * 64;
    if (cidx == 0) { Xin = x; ldx = 6; Din = 6; }
    else { Xin = cat + (cidx - 1) * 64; ldx = 192; Din = 64; }
    float* st0 = stats + (cidx * 2) * 2048;
    float* st1 = stats + (cidx * 2 + 1) * 2048;

    row_sq_kernel<<<T / 256, 256, 0, stream>>>(Xin, ldx, Din, sq);
    if (Din == 6)
      knn_split_kernel<6><<<1024, 256, 0, stream>>>(Xin, ldx, sq, part);
    else
      knn_split_kernel<64><<<1024, 256, 0, stream>>>(Xin, ldx, sq, part);
    knn_merge2_kernel<<<T / 256, 256, 0, stream>>>(part, idx);
    if (Din == 6)
      mlp0_kernel<6><<<512, 256, 0, stream>>>(Xin, ldx, idx, c_w0[cidx], c_b0[cidx], eh0, st0);
    else
      mlp0_kernel<64><<<512, 256, 0, stream>>>(Xin, ldx, idx, c_w0[cidx], c_b0[cidx], eh0, st0);
    fold_kernel<<<17, 256, 0, stream>>>(st0, cInvE, c_g0[cidx], c_be0[cidx],
                                        c_w1[cidx], c_b1[cidx], w1f, b1f, 64, 64);
    mlp1_kernel<<<512, 256, 0, stream>>>(eh0, w1f, b1f, xmax, xmin, st1);
    conv_out_kernel<<<T * 64 / 256, 256, 0, stream>>>(xmax, xmin, st1, cInvE,
                                                      c_g1[cidx], c_be1[cidx], cat, coff);
  }

  float* stl1 = stats + 6 * 2048;
  gemm_kernel<<<(T / 64) * (1024 / 64), 256, 0, stream>>>(
      cat, 192, l1_w, 1024, l1_b, 0, nullptr, stl1, cmax, cmin, 192, 1024);
  pool_finalize_kernel<<<32, 256, 0, stream>>>(cmax, cmin, stl1, cInvT, l1_g, l1_be, pooled);
  po_gemm_kernel<<<8, 256, 0, stream>>>(pooled, m0_w + 192 * 256, m0_b, po);

  float* stm0 = stats + 7 * 2048;
  gemm_kernel<<<(T / 64) * (256 / 64), 256, 0, stream>>>(
      cat, 192, m0_w, 256, po, 1, hm0, stm0, nullptr, nullptr, 192, 256);
  fold_kernel<<<129, 256, 0, stream>>>(stm0, cInvT, m0_g, m0_be, m1_w, m1_b, m1f, m1fb, 256, 128);

  float* stm1 = stats + 8 * 2048;
  gemm_kernel<<<(T / 64) * (128 / 64), 256, 0, stream>>>(
      hm0, 256, m1f, 128, m1fb, 0, hm1, stm1, nullptr, nullptr, 256, 128);
  fold_kernel<<<1, 256, 0, stream>>>(stm1, cInvT, m1_g, m1_be, m2_w, m2_b, m2f, m2fb, 128, 1);
  m2_gemv_kernel<<<T / 4, 256, 0, stream>>>(hm1, m2f, m2fb, out);
}

// Round 8
// 1560.972 us; speedup vs baseline: 1.2003x; 1.2003x over previous
//
#include <hip/hip_runtime.h>
#include <stdint.h>

// ---------------------------------------------------------------------------
// DGCNN forward on MI355X. All fp32. B=8 graphs x N=2048 nodes, D0=6, K=10.
// BN folded into following layer weights; max-pools done on raw activations
// via monotone-affine trick; x5 branch of m0 reduced to [8,1024]@[1024,256].
// R7: kNN merge = parallel shuffle tournament (10 rounds of 16-lane group-min
// + owner-pop), replacing the serialized 16-lane LDS scan whose latency chain
// (~83K cy/block, one partial wave) dominated R4-R6. No msc LDS, no barriers.
// ---------------------------------------------------------------------------

constexpr int T  = 16384;   // total nodes
constexpr int NBG = 8;      // graphs
constexpr int NN = 2048;    // nodes per graph
constexpr int KK = 10;      // kNN
constexpr float BN_EPS = 1e-5f;

__device__ __forceinline__ unsigned fkey(float f) {
  unsigned u = __float_as_uint(f);
  return (u & 0x80000000u) ? ~u : (u | 0x80000000u);
}
__device__ __forceinline__ float funkey(unsigned k) {
  unsigned u = (k & 0x80000000u) ? (k ^ 0x80000000u) : ~k;
  return __uint_as_float(u);
}

__device__ __forceinline__ void ins10(unsigned long long (&b)[KK],
                                      unsigned long long v) {
  b[KK - 1] = v;
#pragma unroll
  for (int s = KK - 1; s > 0; --s)
    if (b[s] < b[s - 1]) {
      unsigned long long t2 = b[s]; b[s] = b[s - 1]; b[s - 1] = t2;
    }
}

// ---------------------------------------------------------------- zero init
__global__ void zero_kernel(float* __restrict__ stats,
                            unsigned* __restrict__ cmax, unsigned* __restrict__ cmin) {
  const int gid = blockIdx.x * blockDim.x + threadIdx.x;
  if (gid < 9 * 2048) stats[gid] = 0.f;
  if (gid < NBG * 1024) { cmax[gid] = 0u; cmin[gid] = 0xFFFFFFFFu; }
}

// ---------------------------------------------------------------- row norms
__global__ void row_sq_kernel(const float* __restrict__ X, int ldx, int D,
                              float* __restrict__ sq) {
  const int t = blockIdx.x * blockDim.x + threadIdx.x;
  if (t >= T) return;
  const float* xr = X + (size_t)t * ldx;
  float s = 0.f;
  for (int d = 0; d < D; ++d) s = fmaf(xr[d], xr[d], s);
  sq[t] = s;
}

// ---------------------------------------------------------------- kNN (j-split)
// Block: 32 rows x 1024 j (jh=blk&1 picks the half). 256 threads: tg=tid>>4
// owns rows {2tg,2tg+1}, tc=tid&15 owns cols [tc*32,+32) of each 512-col
// j-tile (2 tiles). Metric m = sq[j]-2*dot (row-constant sq[i] dropped; same
// order). Per-thread running top-10 with exact row-global reject threshold.
// Merge: 10-round shuffle tournament per 16-lane group -> part[T][2][10].
template<int D>
__global__ __launch_bounds__(256) void knn_split_kernel(
    const float* __restrict__ X, int ldx,
    const float* __restrict__ sq,
    unsigned long long* __restrict__ part /* [T][2][10] */) {
  constexpr int BK = (D == 64) ? 8 : 6;
  constexpr int AF = D * 32;          // As floats [k][row]
  constexpr int BF = BK * 576;        // Bs floats [k][g][36] (16 groups 32+4 pad)
  constexpr int SMEMF = AF + BF + 576; // + sqs [g][36]
  __shared__ __align__(16) float smem[SMEMF];
  float* As = smem;
  float* Bs = smem + AF;
  float* sqs = smem + AF + BF;

  const int tid = threadIdx.x;
  const int blk = blockIdx.x;
  const int b = blk >> 7;             // graph
  const int ib = (blk >> 1) & 63;     // 32-row group
  const int jh = blk & 1;             // j half
  const int i0 = b * NN + ib * 32;
  const int jg0 = b * NN + jh * 1024;
  const int tg = tid >> 4, tc = tid & 15;

  // ---- stage A once: [k][row]
  if constexpr (D == 64) {
    const int r = tid & 31, ks = (tid >> 5) * 8;
    const float* rp = &X[(size_t)(i0 + r) * ldx + ks];
    const float4 v0 = *(const float4*)rp;
    const float4 v1 = *(const float4*)(rp + 4);
    As[(ks + 0) * 32 + r] = v0.x; As[(ks + 1) * 32 + r] = v0.y;
    As[(ks + 2) * 32 + r] = v0.z; As[(ks + 3) * 32 + r] = v0.w;
    As[(ks + 4) * 32 + r] = v1.x; As[(ks + 5) * 32 + r] = v1.y;
    As[(ks + 6) * 32 + r] = v1.z; As[(ks + 7) * 32 + r] = v1.w;
  } else {
    const int r = tid >> 3, k = tid & 7;
    if (k < D) As[k * 32 + r] = X[(size_t)(i0 + r) * ldx + k];
  }

  const unsigned long long initk = 0xFF800000FFFFFFFFULL;  // key(+inf)
  unsigned long long bst0[KK], bst1[KK];
#pragma unroll
  for (int s = 0; s < KK; ++s) { bst0[s] = initk; bst1[s] = initk; }
  const float FINF = __int_as_float(0x7F800000);
  float thr0 = FINF, thr1 = FINF;
  float rowThr0 = FINF, rowThr1 = FINF;

  for (int jt = 0; jt < 2; ++jt) {
    const int jtbase = jg0 + jt * 512;
    float acc0[32] = {}, acc1[32] = {};

    if constexpr (D == 64) {
      for (int kb = 0; kb < 64; kb += 8) {
        __syncthreads();  // prior consumers of Bs/sqs done
#pragma unroll
        for (int h = 0; h < 2; ++h) {
          const int c = tid + h * 256;
          const float* rp = &X[(size_t)(jtbase + c) * ldx + kb];
          const float4 v0 = *(const float4*)rp;
          const float4 v1 = *(const float4*)(rp + 4);
          const int co = (c >> 5) * 36 + (c & 31);
          Bs[0 * 576 + co] = v0.x; Bs[1 * 576 + co] = v0.y;
          Bs[2 * 576 + co] = v0.z; Bs[3 * 576 + co] = v0.w;
          Bs[4 * 576 + co] = v1.x; Bs[5 * 576 + co] = v1.y;
          Bs[6 * 576 + co] = v1.z; Bs[7 * 576 + co] = v1.w;
          if (kb == 0) sqs[co] = sq[jtbase + c];
        }
        __syncthreads();
#pragma unroll
        for (int kk = 0; kk < 8; ++kk) {
          const float2 av = *(const float2*)&As[(kb + kk) * 32 + 2 * tg];
          const float a0 = av.x, a1 = av.y;
          const float* bp = &Bs[kk * 576 + tc * 36];
#pragma unroll
          for (int c4 = 0; c4 < 8; ++c4) {
            const float4 bv = *(const float4*)(bp + c4 * 4);
            acc0[c4 * 4 + 0] = fmaf(a0, bv.x, acc0[c4 * 4 + 0]);
            acc0[c4 * 4 + 1] = fmaf(a0, bv.y, acc0[c4 * 4 + 1]);
            acc0[c4 * 4 + 2] = fmaf(a0, bv.z, acc0[c4 * 4 + 2]);
            acc0[c4 * 4 + 3] = fmaf(a0, bv.w, acc0[c4 * 4 + 3]);
            acc1[c4 * 4 + 0] = fmaf(a1, bv.x, acc1[c4 * 4 + 0]);
            acc1[c4 * 4 + 1] = fmaf(a1, bv.y, acc1[c4 * 4 + 1]);
            acc1[c4 * 4 + 2] = fmaf(a1, bv.z, acc1[c4 * 4 + 2]);
            acc1[c4 * 4 + 3] = fmaf(a1, bv.w, acc1[c4 * 4 + 3]);
          }
        }
      }
    } else {  // D == 6: one staging step per tile
      __syncthreads();
#pragma unroll
      for (int h = 0; h < 2; ++h) {
        const int c = tid + h * 256;
        const float* rp = &X[(size_t)(jtbase + c) * ldx];
        const int co = (c >> 5) * 36 + (c & 31);
#pragma unroll
        for (int k = 0; k < 6; ++k) Bs[k * 576 + co] = rp[k];
        sqs[co] = sq[jtbase + c];
      }
      __syncthreads();
#pragma unroll
      for (int kk = 0; kk < 6; ++kk) {
        const float2 av = *(const float2*)&As[kk * 32 + 2 * tg];
        const float a0 = av.x, a1 = av.y;
        const float* bp = &Bs[kk * 576 + tc * 36];
#pragma unroll
        for (int c4 = 0; c4 < 8; ++c4) {
          const float4 bv = *(const float4*)(bp + c4 * 4);
          acc0[c4 * 4 + 0] = fmaf(a0, bv.x, acc0[c4 * 4 + 0]);
          acc0[c4 * 4 + 1] = fmaf(a0, bv.y, acc0[c4 * 4 + 1]);
          acc0[c4 * 4 + 2] = fmaf(a0, bv.z, acc0[c4 * 4 + 2]);
          acc0[c4 * 4 + 3] = fmaf(a0, bv.w, acc0[c4 * 4 + 3]);
          acc1[c4 * 4 + 0] = fmaf(a1, bv.x, acc1[c4 * 4 + 0]);
          acc1[c4 * 4 + 1] = fmaf(a1, bv.y, acc1[c4 * 4 + 1]);
          acc1[c4 * 4 + 2] = fmaf(a1, bv.z, acc1[c4 * 4 + 2]);
          acc1[c4 * 4 + 3] = fmaf(a1, bv.w, acc1[c4 * 4 + 3]);
        }
      }
    }

    // ---- selection for tile jt: gate on row-global + local thresholds.
    // Exact: per-thread j strictly increases, so equal-m later-j is correctly
    // rejected by the strict < on the local threshold; rowThr is a proven
    // reject bound (some lane already holds 10 better).
#pragma unroll
    for (int c4 = 0; c4 < 8; ++c4) {
      const float4 sv = *(const float4*)&sqs[tc * 36 + c4 * 4];
      const float svv[4] = {sv.x, sv.y, sv.z, sv.w};
#pragma unroll
      for (int u = 0; u < 4; ++u) {
        const int c = c4 * 4 + u;
        const int j = jtbase + tc * 32 + c;
        const float m0 = fmaf(-2.f, acc0[c], svv[u]);
        if (m0 <= rowThr0 && m0 < thr0) {
          ins10(bst0, ((unsigned long long)fkey(m0) << 32) | (unsigned)j);
          thr0 = funkey((unsigned)(bst0[KK - 1] >> 32));
        }
        const float m1 = fmaf(-2.f, acc1[c], svv[u]);
        if (m1 <= rowThr1 && m1 < thr1) {
          ins10(bst1, ((unsigned long long)fkey(m1) << 32) | (unsigned)j);
          thr1 = funkey((unsigned)(bst1[KK - 1] >> 32));
        }
      }
    }
    float r0 = thr0, r1 = thr1;
#pragma unroll
    for (int d = 1; d < 16; d <<= 1) {
      r0 = fminf(r0, __shfl_xor(r0, d, 64));
      r1 = fminf(r1, __shfl_xor(r1, d, 64));
    }
    rowThr0 = r0; rowThr1 = r1;
  }

  // ---- merge: parallel tournament per 16-lane tc-group. Each round: group
  // min of heads (4 shfl_xor u64-min), unique owner pops (keys unique: j is
  // unique and j-columns are lane-partitioned; >=10 real entries per row
  // guaranteed since the union of lane lists contains the row top-10).
  unsigned long long* o0 = part + ((size_t)(i0 + 2 * tg) * 2 + jh) * KK;
  unsigned long long* o1 = part + ((size_t)(i0 + 2 * tg + 1) * 2 + jh) * KK;
#pragma unroll
  for (int s = 0; s < KK; ++s) {
    unsigned long long w0 = bst0[0];
#pragma unroll
    for (int d = 1; d < 16; d <<= 1) {
      const unsigned long long o = __shfl_xor(w0, d, 64);
      w0 = (o < w0) ? o : w0;
    }
    const bool pop0 = (bst0[0] == w0);
#pragma unroll
    for (int q = 0; q < KK - 1; ++q) bst0[q] = pop0 ? bst0[q + 1] : bst0[q];
    if (pop0) bst0[KK - 1] = ~0ULL;
    if (tc == 0) o0[s] = w0;

    unsigned long long w1 = bst1[0];
#pragma unroll
    for (int d = 1; d < 16; d <<= 1) {
      const unsigned long long o = __shfl_xor(w1, d, 64);
      w1 = (o < w1) ? o : w1;
    }
    const bool pop1 = (bst1[0] == w1);
#pragma unroll
    for (int q = 0; q < KK - 1; ++q) bst1[q] = pop1 ? bst1[q + 1] : bst1[q];
    if (pop1) bst1[KK - 1] = ~0ULL;
    if (tc == 1) o1[s] = w1;
  }
}

// final merge of the two j-half partials (20 entries) -> idx
__global__ void knn_merge2_kernel(const unsigned long long* __restrict__ part,
                                  int* __restrict__ idx) {
  const int i = blockIdx.x * blockDim.x + threadIdx.x;
  if (i >= T) return;
  const unsigned long long* p = part + (size_t)i * 2 * KK;
  unsigned long long best[KK];
#pragma unroll
  for (int s = 0; s < KK; ++s) best[s] = ~0ULL;
  for (int q = 0; q < 2 * KK; ++q) {
    const unsigned long long v = p[q];
    if (v < best[KK - 1]) ins10(best, v);
  }
#pragma unroll
  for (int s = 0; s < KK; ++s) idx[i * KK + s] = (int)(best[s] & 0xffffffffu);
}

// ---------------------------------------------------------------- edge MLP0
// h = relu(b0 + xi@(W_A - W_B) + xj@W_B). Wave per 8 nodes, lane = out chan.
template<int D>
__global__ __launch_bounds__(256) void mlp0_kernel(
    const float* __restrict__ X, int ldx,
    const int* __restrict__ idx,
    const float* __restrict__ w0, const float* __restrict__ b0,
    float* __restrict__ eh0, float* __restrict__ stat) {
  const int wv = threadIdx.x >> 6, lane = threadIdx.x & 63;
  const int t0 = (blockIdx.x * 4 + wv) * 8;
  float wB[D], wd[D];
#pragma unroll
  for (int d = 0; d < D; ++d) {
    const float a = w0[d * 64 + lane];
    const float b = w0[(D + d) * 64 + lane];
    wB[d] = b; wd[d] = a - b;
  }
  const float bb = b0[lane];
  float s1 = 0.f, s2 = 0.f;
  for (int tt = 0; tt < 8; ++tt) {
    const int t = t0 + tt;
    const float* xr = X + (size_t)t * ldx;
    float hb = bb;
    if constexpr (D == 64) {
      float h0 = 0.f, h1 = 0.f;
#pragma unroll
      for (int q = 0; q < 16; ++q) {
        const float4 v = *(const float4*)(xr + q * 4);
        h0 = fmaf(v.x, wd[4 * q + 0], h0);
        h1 = fmaf(v.y, wd[4 * q + 1], h1);
        h0 = fmaf(v.z, wd[4 * q + 2], h0);
        h1 = fmaf(v.w, wd[4 * q + 3], h1);
      }
      hb += h0 + h1;
    } else {
#pragma unroll
      for (int d = 0; d < D; ++d) hb = fmaf(xr[d], wd[d], hb);
    }
    for (int k = 0; k < KK; ++k) {
      const int jg = idx[t * KK + k];
      const float* yr = X + (size_t)jg * ldx;
      float h = hb;
      if constexpr (D == 64) {
        float h0 = 0.f, h1 = 0.f;
#pragma unroll
        for (int q = 0; q < 16; ++q) {
          const float4 v = *(const float4*)(yr + q * 4);
          h0 = fmaf(v.x, wB[4 * q + 0], h0);
          h1 = fmaf(v.y, wB[4 * q + 1], h1);
          h0 = fmaf(v.z, wB[4 * q + 2], h0);
          h1 = fmaf(v.w, wB[4 * q + 3], h1);
        }
        h += h0 + h1;
      } else {
#pragma unroll
        for (int d = 0; d < D; ++d) h = fmaf(yr[d], wB[d], h);
      }
      h = fmaxf(h, 0.f);
      eh0[(size_t)(t * KK + k) * 64 + lane] = h;
      s1 += h;
      s2 = fmaf(h, h, s2);
    }
  }
  __shared__ float ls[4][64];
  ls[wv][lane] = s1;
  __syncthreads();
  if (wv == 0) atomicAdd(&stat[lane], ls[0][lane] + ls[1][lane] + ls[2][lane] + ls[3][lane]);
  __syncthreads();
  ls[wv][lane] = s2;
  __syncthreads();
  if (wv == 0) atomicAdd(&stat[1024 + lane], ls[0][lane] + ls[1][lane] + ls[2][lane] + ls[3][lane]);
}

// ---------------------------------------------------------------- BN fold
__global__ void fold_kernel(const float* __restrict__ stat, float cntInv,
                            const float* __restrict__ g, const float* __restrict__ be,
                            const float* __restrict__ W, const float* __restrict__ bias,
                            float* __restrict__ Wf, float* __restrict__ bf,
                            int Cin, int Cout) {
  const int gid = blockIdx.x * blockDim.x + threadIdx.x;
  const int nW = Cin * Cout;
  if (gid < nW) {
    const int d = gid / Cout;
    const float mean = stat[d] * cntInv;
    const float var = fmaf(-mean, mean, stat[1024 + d] * cntInv);
    const float a = g[d] * rsqrtf(var + BN_EPS);
    Wf[gid] = a * W[gid];
  } else if (gid < nW + Cout) {
    const int j = gid - nW;
    float acc = bias[j];
    for (int d = 0; d < Cin; ++d) {
      const float mean = stat[d] * cntInv;
      const float var = fmaf(-mean, mean, stat[1024 + d] * cntInv);
      const float a = g[d] * rsqrtf(var + BN_EPS);
      const float c = fmaf(-mean, a, be[d]);
      acc = fmaf(c, W[d * Cout + j], acc);
    }
    bf[j] = acc;
  }
}

// ---------------------------------------------------------------- edge MLP1
__global__ __launch_bounds__(256) void mlp1_kernel(
    const float* __restrict__ eh0,
    const float* __restrict__ w1f, const float* __restrict__ b1f,
    float* __restrict__ xmax, float* __restrict__ xmin,
    float* __restrict__ stat) {
  const int wv = threadIdx.x >> 6, lane = threadIdx.x & 63;
  const int t0 = (blockIdx.x * 4 + wv) * 8;
  float wc[64];
#pragma unroll
  for (int d = 0; d < 64; ++d) wc[d] = w1f[d * 64 + lane];
  const float bb = b1f[lane];
  float s1 = 0.f, s2 = 0.f;
  for (int tt = 0; tt < 8; ++tt) {
    const int t = t0 + tt;
    float mx = -3.4e38f, mn = 3.4e38f;
#pragma unroll 2
    for (int k = 0; k < KK; ++k) {
      const float* er = eh0 + (size_t)(t * KK + k) * 64;
      float h0 = bb, h1 = 0.f;
#pragma unroll
      for (int q = 0; q < 16; ++q) {
        const float4 v = *(const float4*)(er + q * 4);
        h0 = fmaf(v.x, wc[4 * q + 0], h0);
        h1 = fmaf(v.y, wc[4 * q + 1], h1);
        h0 = fmaf(v.z, wc[4 * q + 2], h0);
        h1 = fmaf(v.w, wc[4 * q + 3], h1);
      }
      const float h = fmaxf(h0 + h1, 0.f);
      mx = fmaxf(mx, h); mn = fminf(mn, h);
      s1 += h; s2 = fmaf(h, h, s2);
    }
    xmax[t * 64 + lane] = mx;
    xmin[t * 64 + lane] = mn;
  }
  __shared__ float ls[4][64];
  ls[wv][lane] = s1;
  __syncthreads();
  if (wv == 0) atomicAdd(&stat[lane], ls[0][lane] + ls[1][lane] + ls[2][lane] + ls[3][lane]);
  __syncthreads();
  ls[wv][lane] = s2;
  __syncthreads();
  if (wv == 0) atomicAdd(&stat[1024 + lane], ls[0][lane] + ls[1][lane] + ls[2][lane] + ls[3][lane]);
}

// ---------------------------------------------------------------- conv output
__global__ void conv_out_kernel(const float* __restrict__ xmax, const float* __restrict__ xmin,
                                const float* __restrict__ stat, float cntInv,
                                const float* __restrict__ g, const float* __restrict__ be,
                                float* __restrict__ cat, int coff) {
  const int gid = blockIdx.x * blockDim.x + threadIdx.x;
  const int c = gid & 63, t = gid >> 6;
  const float mean = stat[c] * cntInv;
  const float var = fmaf(-mean, mean, stat[1024 + c] * cntInv);
  const float a = g[c] * rsqrtf(var + BN_EPS);
  const float cc = fmaf(-mean, a, be[c]);
  const float v = (a >= 0.f) ? fmaf(a, xmax[gid], cc) : fmaf(a, xmin[gid], cc);
  cat[(size_t)t * 192 + coff + c] = v;
}

// ---------------------------------------------------------------- generic GEMM
__global__ __launch_bounds__(256) void gemm_kernel(
    const float* __restrict__ A, int lda,
    const float* __restrict__ Bw, int ldb,
    const float* __restrict__ bias, int biasPerGraph,
    float* __restrict__ C,
    float* __restrict__ stat,
    unsigned* __restrict__ cmax, unsigned* __restrict__ cmin,
    int Kdim, int Ncols) {
  __shared__ float As[32][68];   // transposed A tile [k][row], padded
  __shared__ float Bs[32][64];
  const int tid = threadIdx.x;
  const int nbx = Ncols >> 6;
  const int bx = blockIdx.x % nbx, by = blockIdx.x / nbx;
  const int row0 = by << 6, col0 = bx << 6;
  const int tx = tid & 15, ty = tid >> 4;
  float acc[4][4] = {};
  for (int kb = 0; kb < Kdim; kb += 32) {
    __syncthreads();
    {
      const int r = tid >> 3, fc = tid & 7;
#pragma unroll
      for (int h = 0; h < 2; ++h) {
        const int rr = r + h * 32;
        const float4 va = *(const float4*)&A[(size_t)(row0 + rr) * lda + kb + fc * 4];
        As[fc * 4 + 0][rr] = va.x; As[fc * 4 + 1][rr] = va.y;
        As[fc * 4 + 2][rr] = va.z; As[fc * 4 + 3][rr] = va.w;
      }
      const int kr = tid >> 4, c4 = tid & 15;
#pragma unroll
      for (int h = 0; h < 2; ++h) {
        const int k2 = kr + h * 16;
        *(float4*)&Bs[k2][c4 * 4] =
            *(const float4*)&Bw[(size_t)(kb + k2) * ldb + col0 + c4 * 4];
      }
    }
    __syncthreads();
#pragma unroll
    for (int k = 0; k < 32; ++k) {
      const float4 av = *(const float4*)&As[k][ty * 4];
      const float4 bv = *(const float4*)&Bs[k][tx * 4];
      const float a4[4] = {av.x, av.y, av.z, av.w};
      const float b4[4] = {bv.x, bv.y, bv.z, bv.w};
#pragma unroll
      for (int i = 0; i < 4; ++i)
#pragma unroll
        for (int j = 0; j < 4; ++j) acc[i][j] = fmaf(a4[i], b4[j], acc[i][j]);
    }
  }
  const int graph = row0 >> 11;
  const float* bp = bias + (biasPerGraph ? graph * Ncols : 0) + col0 + tx * 4;
  float v[4][4];
#pragma unroll
  for (int j = 0; j < 4; ++j) {
    const float bj = bp[j];
#pragma unroll
    for (int i = 0; i < 4; ++i) v[i][j] = fmaxf(acc[i][j] + bj, 0.f);
  }
  if (C) {
#pragma unroll
    for (int i = 0; i < 4; ++i) {
      const float4 st = make_float4(v[i][0], v[i][1], v[i][2], v[i][3]);
      *(float4*)&C[(size_t)(row0 + ty * 4 + i) * Ncols + col0 + tx * 4] = st;
    }
  }
  if (stat) {
    __syncthreads();
#pragma unroll
    for (int j = 0; j < 4; ++j)
      As[ty][tx * 4 + j] = v[0][j] + v[1][j] + v[2][j] + v[3][j];
    __syncthreads();
    if (tid < 64) {
      float s = 0.f;
#pragma unroll
      for (int q = 0; q < 16; ++q) s += As[q][tid];
      atomicAdd(&stat[col0 + tid], s);
    }
    __syncthreads();
#pragma unroll
    for (int j = 0; j < 4; ++j) {
      float s = 0.f;
#pragma unroll
      for (int i = 0; i < 4; ++i) s = fmaf(v[i][j], v[i][j], s);
      As[ty][tx * 4 + j] = s;
    }
    __syncthreads();
    if (tid < 64) {
      float s = 0.f;
#pragma unroll
      for (int q = 0; q < 16; ++q) s += As[q][tid];
      atomicAdd(&stat[1024 + col0 + tid], s);
    }
    if (cmax) {
      __syncthreads();
#pragma unroll
      for (int j = 0; j < 4; ++j)
        As[ty][tx * 4 + j] = fmaxf(fmaxf(v[0][j], v[1][j]), fmaxf(v[2][j], v[3][j]));
      __syncthreads();
      if (tid < 64) {
        float s = As[0][tid];
#pragma unroll
        for (int q = 1; q < 16; ++q) s = fmaxf(s, As[q][tid]);
        atomicMax(&cmax[graph * Ncols + col0 + tid], fkey(s));
      }
      __syncthreads();
#pragma unroll
      for (int j = 0; j < 4; ++j)
        As[ty][tx * 4 + j] = fminf(fminf(v[0][j], v[1][j]), fminf(v[2][j], v[3][j]));
      __syncthreads();
      if (tid < 64) {
        float s = As[0][tid];
#pragma unroll
        for (int q = 1; q < 16; ++q) s = fminf(s, As[q][tid]);
        atomicMin(&cmin[graph * Ncols + col0 + tid], fkey(s));
      }
    }
  }
}

// ---------------------------------------------------------------- pooled (normalized)
__global__ void pool_finalize_kernel(const unsigned* __restrict__ cmax,
                                     const unsigned* __restrict__ cmin,
                                     const float* __restrict__ stat, float cntInv,
                                     const float* __restrict__ g, const float* __restrict__ be,
                                     float* __restrict__ pooled) {
  const int gid = blockIdx.x * blockDim.x + threadIdx.x;
  if (gid >= NBG * 1024) return;
  const int col = gid & 1023;
  const float mean = stat[col] * cntInv;
  const float var = fmaf(-mean, mean, stat[1024 + col] * cntInv);
  const float a = g[col] * rsqrtf(var + BN_EPS);
  const float cc = fmaf(-mean, a, be[col]);
  const float fx = funkey(cmax[gid]), fn = funkey(cmin[gid]);
  pooled[gid] = (a >= 0.f) ? fmaf(a, fx, cc) : fmaf(a, fn, cc);
}

// po[b][j] = m0_b[j] + pooled[b] @ m0_w[192:1216]
__global__ void po_gemm_kernel(const float* __restrict__ pooled,
                               const float* __restrict__ w2,
                               const float* __restrict__ m0b,
                               float* __restrict__ po) {
  const int b = blockIdx.x, j = threadIdx.x;
  const float* pr = pooled + b * 1024;
  float a0 = m0b[j], a1 = 0.f, a2 = 0.f, a3 = 0.f;
  for (int d = 0; d < 1024; d += 4) {
    a0 = fmaf(pr[d + 0], w2[(size_t)(d + 0) * 256 + j], a0);
    a1 = fmaf(pr[d + 1], w2[(size_t)(d + 1) * 256 + j], a1);
    a2 = fmaf(pr[d + 2], w2[(size_t)(d + 2) * 256 + j], a2);
    a3 = fmaf(pr[d + 3], w2[(size_t)(d + 3) * 256 + j], a3);
  }
  po[b * 256 + j] = (a0 + a1) + (a2 + a3);
}

// out[t] = hm1[t] @ m2f + b2f   (wave per row, shuffle reduce)
__global__ __launch_bounds__(256) void m2_gemv_kernel(
    const float* __restrict__ hm1, const float* __restrict__ m2f,
    const float* __restrict__ m2fb, float* __restrict__ out) {
  const int wv = threadIdx.x >> 6, lane = threadIdx.x & 63;
  const int t = blockIdx.x * 4 + wv;
  const float* r = hm1 + (size_t)t * 128;
  float v = fmaf(r[lane], m2f[lane], r[64 + lane] * m2f[64 + lane]);
  for (int off = 32; off; off >>= 1) v += __shfl_down(v, off);
  if (lane == 0) out[t] = v + m2fb[0];
}

// ---------------------------------------------------------------------------
extern "C" void kernel_launch(void* const* d_in, const int* in_sizes, int n_in,
                              void* d_out, int out_size, void* d_ws, size_t ws_size,
                              hipStream_t stream) {
  const float* x = (const float*)d_in[0];
  const float* c_w0[3] = {(const float*)d_in[1], (const float*)d_in[9],  (const float*)d_in[17]};
  const float* c_b0[3] = {(const float*)d_in[2], (const float*)d_in[10], (const float*)d_in[18]};
  const float* c_g0[3] = {(const float*)d_in[3], (const float*)d_in[11], (const float*)d_in[19]};
  const float* c_be0[3]= {(const float*)d_in[4], (const float*)d_in[12], (const float*)d_in[20]};
  const float* c_w1[3] = {(const float*)d_in[5], (const float*)d_in[13], (const float*)d_in[21]};
  const float* c_b1[3] = {(const float*)d_in[6], (const float*)d_in[14], (const float*)d_in[22]};
  const float* c_g1[3] = {(const float*)d_in[7], (const float*)d_in[15], (const float*)d_in[23]};
  const float* c_be1[3]= {(const float*)d_in[8], (const float*)d_in[16], (const float*)d_in[24]};
  const float* l1_w = (const float*)d_in[25];
  const float* l1_b = (const float*)d_in[26];
  const float* l1_g = (const float*)d_in[27];
  const float* l1_be= (const float*)d_in[28];
  const float* m0_w = (const float*)d_in[29];
  const float* m0_b = (const float*)d_in[30];
  const float* m0_g = (const float*)d_in[31];
  const float* m0_be= (const float*)d_in[32];
  const float* m1_w = (const float*)d_in[33];
  const float* m1_b = (const float*)d_in[34];
  const float* m1_g = (const float*)d_in[35];
  const float* m1_be= (const float*)d_in[36];
  const float* m2_w = (const float*)d_in[37];
  const float* m2_b = (const float*)d_in[38];
  float* out = (float*)d_out;

  char* ws = (char*)d_ws;
  float*    stats  = (float*)(ws + 0);          // 9 stages x 2048 floats
  unsigned* cmax   = (unsigned*)(ws + 73728);   // [8][1024]
  unsigned* cmin   = (unsigned*)(ws + 106496);
  float*    pooled = (float*)(ws + 139264);     // [8][1024]
  float*    po     = (float*)(ws + 172032);     // [8][256]
  float*    w1f    = (float*)(ws + 180224);     // 64x64
  float*    b1f    = (float*)(ws + 196608);     // 64
  float*    m1f    = (float*)(ws + 196864);     // 256x128
  float*    m1fb   = (float*)(ws + 327936);     // 128
  float*    m2f    = (float*)(ws + 328448);     // 128
  float*    m2fb   = (float*)(ws + 328960);     // 1
  float*    sq     = (float*)(ws + 329216);     // [T]
  int*      idx    = (int*)  (ws + 394752);     // [T][10]
  float*    xmax   = (float*)(ws + 1050112);    // [T][64]
  float*    xmin   = (float*)(ws + 5244416);    // [T][64]
  float*    cat    = (float*)(ws + 9438720);    // [T][192]
  char*     regA   = ws + 22021632;             // 42 MB scratch, time-shared
  unsigned long long* part = (unsigned long long*)regA;  // [T][2][10] u64
  float*    eh0    = (float*)regA;              // [T*10][64] (after knn done)
  float*    hm0    = (float*)regA;              // [T][256]  (after convs)
  float*    hm1    = (float*)(regA + 16777216); // [T][128]

  const float cInvE = 1.f / (float)(T * KK);
  const float cInvT = 1.f / (float)T;

  zero_kernel<<<72, 256, 0, stream>>>(stats, cmax, cmin);

  for (int cidx = 0; cidx < 3; ++cidx) {
    const float* Xin; int ldx, Din;
    const int coff = cidx * 64;
    if (cidx == 0) { Xin = x; ldx = 6; Din = 6; }
    else { Xin = cat + (cidx - 1) * 64; ldx = 192; Din = 64; }
    float* st0 = stats + (cidx * 2) * 2048;
    float* st1 = stats + (cidx * 2 + 1) * 2048;

    row_sq_kernel<<<T / 256, 256, 0, stream>>>(Xin, ldx, Din, sq);
    if (Din == 6)
      knn_split_kernel<6><<<1024, 256, 0, stream>>>(Xin, ldx, sq, part);
    else
      knn_split_kernel<64><<<1024, 256, 0, stream>>>(Xin, ldx, sq, part);
    knn_merge2_kernel<<<T / 256, 256, 0, stream>>>(part, idx);
    if (Din == 6)
      mlp0_kernel<6><<<512, 256, 0, stream>>>(Xin, ldx, idx, c_w0[cidx], c_b0[cidx], eh0, st0);
    else
      mlp0_kernel<64><<<512, 256, 0, stream>>>(Xin, ldx, idx, c_w0[cidx], c_b0[cidx], eh0, st0);
    fold_kernel<<<17, 256, 0, stream>>>(st0, cInvE, c_g0[cidx], c_be0[cidx],
                                        c_w1[cidx], c_b1[cidx], w1f, b1f, 64, 64);
    mlp1_kernel<<<512, 256, 0, stream>>>(eh0, w1f, b1f, xmax, xmin, st1);
    conv_out_kernel<<<T * 64 / 256, 256, 0, stream>>>(xmax, xmin, st1, cInvE,
                                                      c_g1[cidx], c_be1[cidx], cat, coff);
  }

  float* stl1 = stats + 6 * 2048;
  gemm_kernel<<<(T / 64) * (1024 / 64), 256, 0, stream>>>(
      cat, 192, l1_w, 1024, l1_b, 0, nullptr, stl1, cmax, cmin, 192, 1024);
  pool_finalize_kernel<<<32, 256, 0, stream>>>(cmax, cmin, stl1, cInvT, l1_g, l1_be, pooled);
  po_gemm_kernel<<<8, 256, 0, stream>>>(pooled, m0_w + 192 * 256, m0_b, po);

  float* stm0 = stats + 7 * 2048;
  gemm_kernel<<<(T / 64) * (256 / 64), 256, 0, stream>>>(
      cat, 192, m0_w, 256, po, 1, hm0, stm0, nullptr, nullptr, 192, 256);
  fold_kernel<<<129, 256, 0, stream>>>(stm0, cInvT, m0_g, m0_be, m1_w, m1_b, m1f, m1fb, 256, 128);

  float* stm1 = stats + 8 * 2048;
  gemm_kernel<<<(T / 64) * (128 / 64), 256, 0, stream>>>(
      hm0, 256, m1f, 128, m1fb, 0, hm1, stm1, nullptr, nullptr, 256, 128);
  fold_kernel<<<1, 256, 0, stream>>>(stm1, cInvT, m1_g, m1_be, m2_w, m2_b, m2f, m2fb, 128, 1);
  m2_gemv_kernel<<<T / 4, 256, 0, stream>>>(hm1, m2f, m2fb, out);
}

// Round 9
// 1539.444 us; speedup vs baseline: 1.2171x; 1.0140x over previous
//
#include <hip/hip_runtime.h>
#include <stdint.h>

// ---------------------------------------------------------------------------
// DGCNN forward on MI355X. All fp32. B=8 graphs x N=2048 nodes, D0=6, K=10.
// BN folded into following layer weights; max-pools done on raw activations
// via monotone-affine trick; x5 branch of m0 reduced to [8,1024]@[1024,256].
// R8: kNN selection issue-bound fix — (f32 key, i32 j) split top-10 lists
// (1 f32 cmp + 4 cndmask per insert level vs u64's ~7 VALU) and 1 row per
// 16-lane group (16 rows x 1024 j per block, 64 cands/thread, acc[32]) for
// VGPR ~95 -> 5 waves/SIMD. Tournament breaks key ties by j-min reduction;
// part still packed u64 so downstream is unchanged. Exact.
// ---------------------------------------------------------------------------

constexpr int T  = 16384;   // total nodes
constexpr int NBG = 8;      // graphs
constexpr int NN = 2048;    // nodes per graph
constexpr int KK = 10;      // kNN
constexpr float BN_EPS = 1e-5f;

__device__ __forceinline__ unsigned fkey(float f) {
  unsigned u = __float_as_uint(f);
  return (u & 0x80000000u) ? ~u : (u | 0x80000000u);
}
__device__ __forceinline__ float funkey(unsigned k) {
  unsigned u = (k & 0x80000000u) ? (k ^ 0x80000000u) : ~k;
  return __uint_as_float(u);
}

__device__ __forceinline__ void ins10(unsigned long long (&b)[KK],
                                      unsigned long long v) {
  b[KK - 1] = v;
#pragma unroll
  for (int s = KK - 1; s > 0; --s)
    if (b[s] < b[s - 1]) {
      unsigned long long t2 = b[s]; b[s] = b[s - 1]; b[s - 1] = t2;
    }
}

// ---------------------------------------------------------------- zero init
__global__ void zero_kernel(float* __restrict__ stats,
                            unsigned* __restrict__ cmax, unsigned* __restrict__ cmin) {
  const int gid = blockIdx.x * blockDim.x + threadIdx.x;
  if (gid < 9 * 2048) stats[gid] = 0.f;
  if (gid < NBG * 1024) { cmax[gid] = 0u; cmin[gid] = 0xFFFFFFFFu; }
}

// ---------------------------------------------------------------- row norms
__global__ void row_sq_kernel(const float* __restrict__ X, int ldx, int D,
                              float* __restrict__ sq) {
  const int t = blockIdx.x * blockDim.x + threadIdx.x;
  if (t >= T) return;
  const float* xr = X + (size_t)t * ldx;
  float s = 0.f;
  for (int d = 0; d < D; ++d) s = fmaf(xr[d], xr[d], s);
  sq[t] = s;
}

// ---------------------------------------------------------------- kNN
// Block: 16 rows x 1024 j (jh=blk&1 picks the half). 256 threads = 16 groups
// (tg) x 16 lanes (tc); group tg owns row tg, lane tc owns cols [tc*32,+32)
// of each 512-col j-tile (2 tiles). Metric m = sq[j]-2*dot (row-constant
// sq[i] dropped; same order). Per-thread running top-10 as (f32 key, int j)
// with stable strict-< insert (earliest-j among float-equal keys; exact) and
// exact row-reject threshold (m <= rowThr non-strict keeps boundary ties).
// Merge: 10-round tournament: group key-min, tie-broken by j-min; store as
// packed u64 -> part[T][2][10].
template<int D>
__global__ __launch_bounds__(256) void knn_split_kernel(
    const float* __restrict__ X, int ldx,
    const float* __restrict__ sq,
    unsigned long long* __restrict__ part /* [T][2][10] */) {
  constexpr int BK = (D == 64) ? 8 : 6;
  constexpr int AF = D * 16;          // As floats [k][row]
  constexpr int BF = BK * 576;        // Bs floats [k][g][36] (16 groups 32+4 pad)
  constexpr int SMEMF = AF + BF + 576; // + sqs [g][36]
  __shared__ __align__(16) float smem[SMEMF];
  float* As = smem;
  float* Bs = smem + AF;
  float* sqs = smem + AF + BF;

  const int tid = threadIdx.x;
  const int blk = blockIdx.x;
  const int b = blk >> 8;             // graph (256 blocks/graph)
  const int ib = (blk >> 1) & 127;    // 16-row group
  const int jh = blk & 1;             // j half
  const int i0 = b * NN + ib * 16;
  const int jg0 = b * NN + jh * 1024;
  const int tg = tid >> 4, tc = tid & 15;

  // ---- stage A once: [k][row] (16 rows)
  if constexpr (D == 64) {
    const int r = tid & 15, kq = tid >> 4;  // kq 0..15, 4 floats each
    const float4 v = *(const float4*)&X[(size_t)(i0 + r) * ldx + kq * 4];
    As[(kq * 4 + 0) * 16 + r] = v.x; As[(kq * 4 + 1) * 16 + r] = v.y;
    As[(kq * 4 + 2) * 16 + r] = v.z; As[(kq * 4 + 3) * 16 + r] = v.w;
  } else {
    const int r = tid & 15, k = tid >> 4;
    if (k < D) As[k * 16 + r] = X[(size_t)(i0 + r) * ldx + k];
  }

  const float FINF = __int_as_float(0x7F800000);
  float bk[KK]; int bj[KK];
#pragma unroll
  for (int s = 0; s < KK; ++s) { bk[s] = FINF; bj[s] = 0; }
  float thr = FINF, rowThr = FINF;

  for (int jt = 0; jt < 2; ++jt) {
    const int jtbase = jg0 + jt * 512;
    float acc[32] = {};

    if constexpr (D == 64) {
      for (int kb = 0; kb < 64; kb += 8) {
        __syncthreads();  // prior consumers of Bs/sqs done
#pragma unroll
        for (int h = 0; h < 2; ++h) {
          const int c = tid + h * 256;
          const float* rp = &X[(size_t)(jtbase + c) * ldx + kb];
          const float4 v0 = *(const float4*)rp;
          const float4 v1 = *(const float4*)(rp + 4);
          const int co = (c >> 5) * 36 + (c & 31);
          Bs[0 * 576 + co] = v0.x; Bs[1 * 576 + co] = v0.y;
          Bs[2 * 576 + co] = v0.z; Bs[3 * 576 + co] = v0.w;
          Bs[4 * 576 + co] = v1.x; Bs[5 * 576 + co] = v1.y;
          Bs[6 * 576 + co] = v1.z; Bs[7 * 576 + co] = v1.w;
          if (kb == 0) sqs[co] = sq[jtbase + c];
        }
        __syncthreads();
#pragma unroll
        for (int kk = 0; kk < 8; ++kk) {
          const float a0 = As[(kb + kk) * 16 + tg];
          const float* bp = &Bs[kk * 576 + tc * 36];
#pragma unroll
          for (int c4 = 0; c4 < 8; ++c4) {
            const float4 bv = *(const float4*)(bp + c4 * 4);
            acc[c4 * 4 + 0] = fmaf(a0, bv.x, acc[c4 * 4 + 0]);
            acc[c4 * 4 + 1] = fmaf(a0, bv.y, acc[c4 * 4 + 1]);
            acc[c4 * 4 + 2] = fmaf(a0, bv.z, acc[c4 * 4 + 2]);
            acc[c4 * 4 + 3] = fmaf(a0, bv.w, acc[c4 * 4 + 3]);
          }
        }
      }
    } else {  // D == 6: one staging step per tile
      __syncthreads();
#pragma unroll
      for (int h = 0; h < 2; ++h) {
        const int c = tid + h * 256;
        const float* rp = &X[(size_t)(jtbase + c) * ldx];
        const int co = (c >> 5) * 36 + (c & 31);
#pragma unroll
        for (int k = 0; k < 6; ++k) Bs[k * 576 + co] = rp[k];
        sqs[co] = sq[jtbase + c];
      }
      __syncthreads();
#pragma unroll
      for (int kk = 0; kk < 6; ++kk) {
        const float a0 = As[kk * 16 + tg];
        const float* bp = &Bs[kk * 576 + tc * 36];
#pragma unroll
        for (int c4 = 0; c4 < 8; ++c4) {
          const float4 bv = *(const float4*)(bp + c4 * 4);
          acc[c4 * 4 + 0] = fmaf(a0, bv.x, acc[c4 * 4 + 0]);
          acc[c4 * 4 + 1] = fmaf(a0, bv.y, acc[c4 * 4 + 1]);
          acc[c4 * 4 + 2] = fmaf(a0, bv.z, acc[c4 * 4 + 2]);
          acc[c4 * 4 + 3] = fmaf(a0, bv.w, acc[c4 * 4 + 3]);
        }
      }
    }

    // ---- selection for tile jt. Stable strict-< insert: among float-equal
    // keys the earlier (smaller-j, since per-lane j ascends) stays first —
    // exact (matches u64 (key|j) order). Row gate non-strict (<=) so
    // boundary ties survive to the tournament's j tie-break.
#pragma unroll
    for (int c4 = 0; c4 < 8; ++c4) {
      const float4 sv = *(const float4*)&sqs[tc * 36 + c4 * 4];
      const float svv[4] = {sv.x, sv.y, sv.z, sv.w};
#pragma unroll
      for (int u = 0; u < 4; ++u) {
        const int c = c4 * 4 + u;
        const int j = jtbase + tc * 32 + c;
        const float m = fmaf(-2.f, acc[c], svv[u]);
        if (m <= rowThr && m < thr) {
          bk[KK - 1] = m; bj[KK - 1] = j;
#pragma unroll
          for (int s = KK - 1; s > 0; --s) {
            const bool sw = bk[s] < bk[s - 1];
            const float ka = bk[s - 1], kb2 = bk[s];
            bk[s - 1] = sw ? kb2 : ka; bk[s] = sw ? ka : kb2;
            const int ja = bj[s - 1], jb2 = bj[s];
            bj[s - 1] = sw ? jb2 : ja; bj[s] = sw ? ja : jb2;
          }
          thr = bk[KK - 1];
        }
      }
    }
    float r0 = thr;
#pragma unroll
    for (int d = 1; d < 16; d <<= 1) r0 = fminf(r0, __shfl_xor(r0, d, 64));
    rowThr = r0;
  }

  // ---- merge: 10-round tournament per 16-lane group. Round: group key-min
  // (4 f32 shfl), owner = key-equal lanes, tie-break by j-min (4 i32 shfl);
  // unique owner pops. Group holds >=10 real entries (the row's true top-10
  // all pass the gates), so 10 rounds extract the exact sorted top-10.
  unsigned long long* o = part + ((size_t)(i0 + tg) * 2 + jh) * KK;
#pragma unroll
  for (int s = 0; s < KK; ++s) {
    float w = bk[0];
#pragma unroll
    for (int d = 1; d < 16; d <<= 1) w = fminf(w, __shfl_xor(w, d, 64));
    int cj = (bk[0] == w) ? bj[0] : 0x7FFFFFFF;
#pragma unroll
    for (int d = 1; d < 16; d <<= 1) {
      const int oc = __shfl_xor(cj, d, 64);
      cj = (oc < cj) ? oc : cj;
    }
    const bool pop = (bk[0] == w) && (bj[0] == cj);
#pragma unroll
    for (int q = 0; q < KK - 1; ++q) {
      bk[q] = pop ? bk[q + 1] : bk[q];
      bj[q] = pop ? bj[q + 1] : bj[q];
    }
    if (pop) bk[KK - 1] = FINF;
    if (tc == 0)
      o[s] = ((unsigned long long)fkey(w) << 32) | (unsigned)cj;
  }
}

// final merge of the two j-half partials (20 entries) -> idx
__global__ void knn_merge2_kernel(const unsigned long long* __restrict__ part,
                                  int* __restrict__ idx) {
  const int i = blockIdx.x * blockDim.x + threadIdx.x;
  if (i >= T) return;
  const unsigned long long* p = part + (size_t)i * 2 * KK;
  unsigned long long best[KK];
#pragma unroll
  for (int s = 0; s < KK; ++s) best[s] = ~0ULL;
  for (int q = 0; q < 2 * KK; ++q) {
    const unsigned long long v = p[q];
    if (v < best[KK - 1]) ins10(best, v);
  }
#pragma unroll
  for (int s = 0; s < KK; ++s) idx[i * KK + s] = (int)(best[s] & 0xffffffffu);
}

// ---------------------------------------------------------------- edge MLP0
// h = relu(b0 + xi@(W_A - W_B) + xj@W_B). Wave per 8 nodes, lane = out chan.
template<int D>
__global__ __launch_bounds__(256) void mlp0_kernel(
    const float* __restrict__ X, int ldx,
    const int* __restrict__ idx,
    const float* __restrict__ w0, const float* __restrict__ b0,
    float* __restrict__ eh0, float* __restrict__ stat) {
  const int wv = threadIdx.x >> 6, lane = threadIdx.x & 63;
  const int t0 = (blockIdx.x * 4 + wv) * 8;
  float wB[D], wd[D];
#pragma unroll
  for (int d = 0; d < D; ++d) {
    const float a = w0[d * 64 + lane];
    const float b = w0[(D + d) * 64 + lane];
    wB[d] = b; wd[d] = a - b;
  }
  const float bb = b0[lane];
  float s1 = 0.f, s2 = 0.f;
  for (int tt = 0; tt < 8; ++tt) {
    const int t = t0 + tt;
    const float* xr = X + (size_t)t * ldx;
    float hb = bb;
    if constexpr (D == 64) {
      float h0 = 0.f, h1 = 0.f;
#pragma unroll
      for (int q = 0; q < 16; ++q) {
        const float4 v = *(const float4*)(xr + q * 4);
        h0 = fmaf(v.x, wd[4 * q + 0], h0);
        h1 = fmaf(v.y, wd[4 * q + 1], h1);
        h0 = fmaf(v.z, wd[4 * q + 2], h0);
        h1 = fmaf(v.w, wd[4 * q + 3], h1);
      }
      hb += h0 + h1;
    } else {
#pragma unroll
      for (int d = 0; d < D; ++d) hb = fmaf(xr[d], wd[d], hb);
    }
    for (int k = 0; k < KK; ++k) {
      const int jg = idx[t * KK + k];
      const float* yr = X + (size_t)jg * ldx;
      float h = hb;
      if constexpr (D == 64) {
        float h0 = 0.f, h1 = 0.f;
#pragma unroll
        for (int q = 0; q < 16; ++q) {
          const float4 v = *(const float4*)(yr + q * 4);
          h0 = fmaf(v.x, wB[4 * q + 0], h0);
          h1 = fmaf(v.y, wB[4 * q + 1], h1);
          h0 = fmaf(v.z, wB[4 * q + 2], h0);
          h1 = fmaf(v.w, wB[4 * q + 3], h1);
        }
        h += h0 + h1;
      } else {
#pragma unroll
        for (int d = 0; d < D; ++d) h = fmaf(yr[d], wB[d], h);
      }
      h = fmaxf(h, 0.f);
      eh0[(size_t)(t * KK + k) * 64 + lane] = h;
      s1 += h;
      s2 = fmaf(h, h, s2);
    }
  }
  __shared__ float ls[4][64];
  ls[wv][lane] = s1;
  __syncthreads();
  if (wv == 0) atomicAdd(&stat[lane], ls[0][lane] + ls[1][lane] + ls[2][lane] + ls[3][lane]);
  __syncthreads();
  ls[wv][lane] = s2;
  __syncthreads();
  if (wv == 0) atomicAdd(&stat[1024 + lane], ls[0][lane] + ls[1][lane] + ls[2][lane] + ls[3][lane]);
}

// ---------------------------------------------------------------- BN fold
__global__ void fold_kernel(const float* __restrict__ stat, float cntInv,
                            const float* __restrict__ g, const float* __restrict__ be,
                            const float* __restrict__ W, const float* __restrict__ bias,
                            float* __restrict__ Wf, float* __restrict__ bf,
                            int Cin, int Cout) {
  const int gid = blockIdx.x * blockDim.x + threadIdx.x;
  const int nW = Cin * Cout;
  if (gid < nW) {
    const int d = gid / Cout;
    const float mean = stat[d] * cntInv;
    const float var = fmaf(-mean, mean, stat[1024 + d] * cntInv);
    const float a = g[d] * rsqrtf(var + BN_EPS);
    Wf[gid] = a * W[gid];
  } else if (gid < nW + Cout) {
    const int j = gid - nW;
    float acc = bias[j];
    for (int d = 0; d < Cin; ++d) {
      const float mean = stat[d] * cntInv;
      const float var = fmaf(-mean, mean, stat[1024 + d] * cntInv);
      const float a = g[d] * rsqrtf(var + BN_EPS);
      const float c = fmaf(-mean, a, be[d]);
      acc = fmaf(c, W[d * Cout + j], acc);
    }
    bf[j] = acc;
  }
}

// ---------------------------------------------------------------- edge MLP1
__global__ __launch_bounds__(256) void mlp1_kernel(
    const float* __restrict__ eh0,
    const float* __restrict__ w1f, const float* __restrict__ b1f,
    float* __restrict__ xmax, float* __restrict__ xmin,
    float* __restrict__ stat) {
  const int wv = threadIdx.x >> 6, lane = threadIdx.x & 63;
  const int t0 = (blockIdx.x * 4 + wv) * 8;
  float wc[64];
#pragma unroll
  for (int d = 0; d < 64; ++d) wc[d] = w1f[d * 64 + lane];
  const float bb = b1f[lane];
  float s1 = 0.f, s2 = 0.f;
  for (int tt = 0; tt < 8; ++tt) {
    const int t = t0 + tt;
    float mx = -3.4e38f, mn = 3.4e38f;
#pragma unroll 2
    for (int k = 0; k < KK; ++k) {
      const float* er = eh0 + (size_t)(t * KK + k) * 64;
      float h0 = bb, h1 = 0.f;
#pragma unroll
      for (int q = 0; q < 16; ++q) {
        const float4 v = *(const float4*)(er + q * 4);
        h0 = fmaf(v.x, wc[4 * q + 0], h0);
        h1 = fmaf(v.y, wc[4 * q + 1], h1);
        h0 = fmaf(v.z, wc[4 * q + 2], h0);
        h1 = fmaf(v.w, wc[4 * q + 3], h1);
      }
      const float h = fmaxf(h0 + h1, 0.f);
      mx = fmaxf(mx, h); mn = fminf(mn, h);
      s1 += h; s2 = fmaf(h, h, s2);
    }
    xmax[t * 64 + lane] = mx;
    xmin[t * 64 + lane] = mn;
  }
  __shared__ float ls[4][64];
  ls[wv][lane] = s1;
  __syncthreads();
  if (wv == 0) atomicAdd(&stat[lane], ls[0][lane] + ls[1][lane] + ls[2][lane] + ls[3][lane]);
  __syncthreads();
  ls[wv][lane] = s2;
  __syncthreads();
  if (wv == 0) atomicAdd(&stat[1024 + lane], ls[0][lane] + ls[1][lane] + ls[2][lane] + ls[3][lane]);
}

// ---------------------------------------------------------------- conv output
__global__ void conv_out_kernel(const float* __restrict__ xmax, const float* __restrict__ xmin,
                                const float* __restrict__ stat, float cntInv,
                                const float* __restrict__ g, const float* __restrict__ be,
                                float* __restrict__ cat, int coff) {
  const int gid = blockIdx.x * blockDim.x + threadIdx.x;
  const int c = gid & 63, t = gid >> 6;
  const float mean = stat[c] * cntInv;
  const float var = fmaf(-mean, mean, stat[1024 + c] * cntInv);
  const float a = g[c] * rsqrtf(var + BN_EPS);
  const float cc = fmaf(-mean, a, be[c]);
  const float v = (a >= 0.f) ? fmaf(a, xmax[gid], cc) : fmaf(a, xmin[gid], cc);
  cat[(size_t)t * 192 + coff + c] = v;
}

// ---------------------------------------------------------------- generic GEMM
__global__ __launch_bounds__(256) void gemm_kernel(
    const float* __restrict__ A, int lda,
    const float* __restrict__ Bw, int ldb,
    const float* __restrict__ bias, int biasPerGraph,
    float* __restrict__ C,
    float* __restrict__ stat,
    unsigned* __restrict__ cmax, unsigned* __restrict__ cmin,
    int Kdim, int Ncols) {
  __shared__ float As[32][68];   // transposed A tile [k][row], padded
  __shared__ float Bs[32][64];
  const int tid = threadIdx.x;
  const int nbx = Ncols >> 6;
  const int bx = blockIdx.x % nbx, by = blockIdx.x / nbx;
  const int row0 = by << 6, col0 = bx << 6;
  const int tx = tid & 15, ty = tid >> 4;
  float acc[4][4] = {};
  for (int kb = 0; kb < Kdim; kb += 32) {
    __syncthreads();
    {
      const int r = tid >> 3, fc = tid & 7;
#pragma unroll
      for (int h = 0; h < 2; ++h) {
        const int rr = r + h * 32;
        const float4 va = *(const float4*)&A[(size_t)(row0 + rr) * lda + kb + fc * 4];
        As[fc * 4 + 0][rr] = va.x; As[fc * 4 + 1][rr] = va.y;
        As[fc * 4 + 2][rr] = va.z; As[fc * 4 + 3][rr] = va.w;
      }
      const int kr = tid >> 4, c4 = tid & 15;
#pragma unroll
      for (int h = 0; h < 2; ++h) {
        const int k2 = kr + h * 16;
        *(float4*)&Bs[k2][c4 * 4] =
            *(const float4*)&Bw[(size_t)(kb + k2) * ldb + col0 + c4 * 4];
      }
    }
    __syncthreads();
#pragma unroll
    for (int k = 0; k < 32; ++k) {
      const float4 av = *(const float4*)&As[k][ty * 4];
      const float4 bv = *(const float4*)&Bs[k][tx * 4];
      const float a4[4] = {av.x, av.y, av.z, av.w};
      const float b4[4] = {bv.x, bv.y, bv.z, bv.w};
#pragma unroll
      for (int i = 0; i < 4; ++i)
#pragma unroll
        for (int j = 0; j < 4; ++j) acc[i][j] = fmaf(a4[i], b4[j], acc[i][j]);
    }
  }
  const int graph = row0 >> 11;
  const float* bp = bias + (biasPerGraph ? graph * Ncols : 0) + col0 + tx * 4;
  float v[4][4];
#pragma unroll
  for (int j = 0; j < 4; ++j) {
    const float bj = bp[j];
#pragma unroll
    for (int i = 0; i < 4; ++i) v[i][j] = fmaxf(acc[i][j] + bj, 0.f);
  }
  if (C) {
#pragma unroll
    for (int i = 0; i < 4; ++i) {
      const float4 st = make_float4(v[i][0], v[i][1], v[i][2], v[i][3]);
      *(float4*)&C[(size_t)(row0 + ty * 4 + i) * Ncols + col0 + tx * 4] = st;
    }
  }
  if (stat) {
    __syncthreads();
#pragma unroll
    for (int j = 0; j < 4; ++j)
      As[ty][tx * 4 + j] = v[0][j] + v[1][j] + v[2][j] + v[3][j];
    __syncthreads();
    if (tid < 64) {
      float s = 0.f;
#pragma unroll
      for (int q = 0; q < 16; ++q) s += As[q][tid];
      atomicAdd(&stat[col0 + tid], s);
    }
    __syncthreads();
#pragma unroll
    for (int j = 0; j < 4; ++j) {
      float s = 0.f;
#pragma unroll
      for (int i = 0; i < 4; ++i) s = fmaf(v[i][j], v[i][j], s);
      As[ty][tx * 4 + j] = s;
    }
    __syncthreads();
    if (tid < 64) {
      float s = 0.f;
#pragma unroll
      for (int q = 0; q < 16; ++q) s += As[q][tid];
      atomicAdd(&stat[1024 + col0 + tid], s);
    }
    if (cmax) {
      __syncthreads();
#pragma unroll
      for (int j = 0; j < 4; ++j)
        As[ty][tx * 4 + j] = fmaxf(fmaxf(v[0][j], v[1][j]), fmaxf(v[2][j], v[3][j]));
      __syncthreads();
      if (tid < 64) {
        float s = As[0][tid];
#pragma unroll
        for (int q = 1; q < 16; ++q) s = fmaxf(s, As[q][tid]);
        atomicMax(&cmax[graph * Ncols + col0 + tid], fkey(s));
      }
      __syncthreads();
#pragma unroll
      for (int j = 0; j < 4; ++j)
        As[ty][tx * 4 + j] = fminf(fminf(v[0][j], v[1][j]), fminf(v[2][j], v[3][j]));
      __syncthreads();
      if (tid < 64) {
        float s = As[0][tid];
#pragma unroll
        for (int q = 1; q < 16; ++q) s = fminf(s, As[q][tid]);
        atomicMin(&cmin[graph * Ncols + col0 + tid], fkey(s));
      }
    }
  }
}

// ---------------------------------------------------------------- pooled (normalized)
__global__ void pool_finalize_kernel(const unsigned* __restrict__ cmax,
                                     const unsigned* __restrict__ cmin,
                                     const float* __restrict__ stat, float cntInv,
                                     const float* __restrict__ g, const float* __restrict__ be,
                                     float* __restrict__ pooled) {
  const int gid = blockIdx.x * blockDim.x + threadIdx.x;
  if (gid >= NBG * 1024) return;
  const int col = gid & 1023;
  const float mean = stat[col] * cntInv;
  const float var = fmaf(-mean, mean, stat[1024 + col] * cntInv);
  const float a = g[col] * rsqrtf(var + BN_EPS);
  const float cc = fmaf(-mean, a, be[col]);
  const float fx = funkey(cmax[gid]), fn = funkey(cmin[gid]);
  pooled[gid] = (a >= 0.f) ? fmaf(a, fx, cc) : fmaf(a, fn, cc);
}

// po[b][j] = m0_b[j] + pooled[b] @ m0_w[192:1216]
__global__ void po_gemm_kernel(const float* __restrict__ pooled,
                               const float* __restrict__ w2,
                               const float* __restrict__ m0b,
                               float* __restrict__ po) {
  const int b = blockIdx.x, j = threadIdx.x;
  const float* pr = pooled + b * 1024;
  float a0 = m0b[j], a1 = 0.f, a2 = 0.f, a3 = 0.f;
  for (int d = 0; d < 1024; d += 4) {
    a0 = fmaf(pr[d + 0], w2[(size_t)(d + 0) * 256 + j], a0);
    a1 = fmaf(pr[d + 1], w2[(size_t)(d + 1) * 256 + j], a1);
    a2 = fmaf(pr[d + 2], w2[(size_t)(d + 2) * 256 + j], a2);
    a3 = fmaf(pr[d + 3], w2[(size_t)(d + 3) * 256 + j], a3);
  }
  po[b * 256 + j] = (a0 + a1) + (a2 + a3);
}

// out[t] = hm1[t] @ m2f + b2f   (wave per row, shuffle reduce)
__global__ __launch_bounds__(256) void m2_gemv_kernel(
    const float* __restrict__ hm1, const float* __restrict__ m2f,
    const float* __restrict__ m2fb, float* __restrict__ out) {
  const int wv = threadIdx.x >> 6, lane = threadIdx.x & 63;
  const int t = blockIdx.x * 4 + wv;
  const float* r = hm1 + (size_t)t * 128;
  float v = fmaf(r[lane], m2f[lane], r[64 + lane] * m2f[64 + lane]);
  for (int off = 32; off; off >>= 1) v += __shfl_down(v, off);
  if (lane == 0) out[t] = v + m2fb[0];
}

// ---------------------------------------------------------------------------
extern "C" void kernel_launch(void* const* d_in, const int* in_sizes, int n_in,
                              void* d_out, int out_size, void* d_ws, size_t ws_size,
                              hipStream_t stream) {
  const float* x = (const float*)d_in[0];
  const float* c_w0[3] = {(const float*)d_in[1], (const float*)d_in[9],  (const float*)d_in[17]};
  const float* c_b0[3] = {(const float*)d_in[2], (const float*)d_in[10], (const float*)d_in[18]};
  const float* c_g0[3] = {(const float*)d_in[3], (const float*)d_in[11], (const float*)d_in[19]};
  const float* c_be0[3]= {(const float*)d_in[4], (const float*)d_in[12], (const float*)d_in[20]};
  const float* c_w1[3] = {(const float*)d_in[5], (const float*)d_in[13], (const float*)d_in[21]};
  const float* c_b1[3] = {(const float*)d_in[6], (const float*)d_in[14], (const float*)d_in[22]};
  const float* c_g1[3] = {(const float*)d_in[7], (const float*)d_in[15], (const float*)d_in[23]};
  const float* c_be1[3]= {(const float*)d_in[8], (const float*)d_in[16], (const float*)d_in[24]};
  const float* l1_w = (const float*)d_in[25];
  const float* l1_b = (const float*)d_in[26];
  const float* l1_g = (const float*)d_in[27];
  const float* l1_be= (const float*)d_in[28];
  const float* m0_w = (const float*)d_in[29];
  const float* m0_b = (const float*)d_in[30];
  const float* m0_g = (const float*)d_in[31];
  const float* m0_be= (const float*)d_in[32];
  const float* m1_w = (const float*)d_in[33];
  const float* m1_b = (const float*)d_in[34];
  const float* m1_g = (const float*)d_in[35];
  const float* m1_be= (const float*)d_in[36];
  const float* m2_w = (const float*)d_in[37];
  const float* m2_b = (const float*)d_in[38];
  float* out = (float*)d_out;

  char* ws = (char*)d_ws;
  float*    stats  = (float*)(ws + 0);          // 9 stages x 2048 floats
  unsigned* cmax   = (unsigned*)(ws + 73728);   // [8][1024]
  unsigned* cmin   = (unsigned*)(ws + 106496);
  float*    pooled = (float*)(ws + 139264);     // [8][1024]
  float*    po     = (float*)(ws + 172032);     // [8][256]
  float*    w1f    = (float*)(ws + 180224);     // 64x64
  float*    b1f    = (float*)(ws + 196608);     // 64
  float*    m1f    = (float*)(ws + 196864);     // 256x128
  float*    m1fb   = (float*)(ws + 327936);     // 128
  float*    m2f    = (float*)(ws + 328448);     // 128
  float*    m2fb   = (float*)(ws + 328960);     // 1
  float*    sq     = (float*)(ws + 329216);     // [T]
  int*      idx    = (int*)  (ws + 394752);     // [T][10]
  float*    xmax   = (float*)(ws + 1050112);    // [T][64]
  float*    xmin   = (float*)(ws + 5244416);    // [T][64]
  float*    cat    = (float*)(ws + 9438720);    // [T][192]
  char*     regA   = ws + 22021632;             // 42 MB scratch, time-shared
  unsigned long long* part = (unsigned long long*)regA;  // [T][2][10] u64
  float*    eh0    = (float*)regA;              // [T*10][64] (after knn done)
  float*    hm0    = (float*)regA;              // [T][256]  (after convs)
  float*    hm1    = (float*)(regA + 16777216); // [T][128]

  const float cInvE = 1.f / (float)(T * KK);
  const float cInvT = 1.f / (float)T;

  zero_kernel<<<72, 256, 0, stream>>>(stats, cmax, cmin);

  for (int cidx = 0; cidx < 3; ++cidx) {
    const float* Xin; int ldx, Din;
    const int coff = cidx * 64;
    if (cidx == 0) { Xin = x; ldx = 6; Din = 6; }
    else { Xin = cat + (cidx - 1) * 64; ldx = 192; Din = 64; }
    float* st0 = stats + (cidx * 2) * 2048;
    float* st1 = stats + (cidx * 2 + 1) * 2048;

    row_sq_kernel<<<T / 256, 256, 0, stream>>>(Xin, ldx, Din, sq);
    if (Din == 6)
      knn_split_kernel<6><<<2048, 256, 0, stream>>>(Xin, ldx, sq, part);
    else
      knn_split_kernel<64><<<2048, 256, 0, stream>>>(Xin, ldx, sq, part);
    knn_merge2_kernel<<<T / 256, 256, 0, stream>>>(part, idx);
    if (Din == 6)
      mlp0_kernel<6><<<512, 256, 0, stream>>>(Xin, ldx, idx, c_w0[cidx], c_b0[cidx], eh0, st0);
    else
      mlp0_kernel<64><<<512, 256, 0, stream>>>(Xin, ldx, idx, c_w0[cidx], c_b0[cidx], eh0, st0);
    fold_kernel<<<17, 256, 0, stream>>>(st0, cInvE, c_g0[cidx], c_be0[cidx],
                                        c_w1[cidx], c_b1[cidx], w1f, b1f, 64, 64);
    mlp1_kernel<<<512, 256, 0, stream>>>(eh0, w1f, b1f, xmax, xmin, st1);
    conv_out_kernel<<<T * 64 / 256, 256, 0, stream>>>(xmax, xmin, st1, cInvE,
                                                      c_g1[cidx], c_be1[cidx], cat, coff);
  }

  float* stl1 = stats + 6 * 2048;
  gemm_kernel<<<(T / 64) * (1024 / 64), 256, 0, stream>>>(
      cat, 192, l1_w, 1024, l1_b, 0, nullptr, stl1, cmax, cmin, 192, 1024);
  pool_finalize_kernel<<<32, 256, 0, stream>>>(cmax, cmin, stl1, cInvT, l1_g, l1_be, pooled);
  po_gemm_kernel<<<8, 256, 0, stream>>>(pooled, m0_w + 192 * 256, m0_b, po);

  float* stm0 = stats + 7 * 2048;
  gemm_kernel<<<(T / 64) * (256 / 64), 256, 0, stream>>>(
      cat, 192, m0_w, 256, po, 1, hm0, stm0, nullptr, nullptr, 192, 256);
  fold_kernel<<<129, 256, 0, stream>>>(stm0, cInvT, m0_g, m0_be, m1_w, m1_b, m1f, m1fb, 256, 128);

  float* stm1 = stats + 8 * 2048;
  gemm_kernel<<<(T / 64) * (128 / 64), 256, 0, stream>>>(
      hm0, 256, m1f, 128, m1fb, 0, hm1, stm1, nullptr, nullptr, 256, 128);
  fold_kernel<<<1, 256, 0, stream>>>(stm1, cInvT, m1_g, m1_be, m2_w, m2_b, m2f, m2fb, 128, 1);
  m2_gemv_kernel<<<T / 4, 256, 0, stream>>>(hm1, m2f, m2fb, out);
}